// Round 1
// baseline (1874.075 us; speedup 1.0000x reference)
//
#include <hip/hip_runtime.h>
#include <cstddef>

// Problem constants (B=16, N=4096=64x64, C=256, 4 heads x 64, 4x4 windows, 4x4 pool)
#define SCALE 0.125f
#define LN_EPS 1e-6f

// ---------------------------------------------------------------------------
// K1: fused per-window kernel. One block per (b, 4x4 spatial window).
//   - load x tile [16 tokens][256 ch] to LDS
//   - qkv = x @ Wqkv^T + b  (16x768, K=256)
//   - 4-head window attention (16 tokens)
//   - z = x + attn, LayerNorm over C per token
//   - write LN result to ln_out, window-mean to pooled
// LDS: 16KB (xt) + 48KB (qkv) = 64KB
// ---------------------------------------------------------------------------
__global__ __launch_bounds__(256) void k_win(
    const float* __restrict__ x, const float* __restrict__ wqkv,
    const float* __restrict__ bqkv, const float* __restrict__ gnw,
    const float* __restrict__ gnb, float* __restrict__ ln_out,
    float* __restrict__ pooled)
{
    __shared__ float xt[16][256];        // x tile -> z -> y (LN out)
    __shared__ float qkv[12][16][64];    // [seg*4+head][token][d]

    const int tid = threadIdx.x;
    const int blk = blockIdx.x;
    const int b   = blk >> 8;
    const int win = blk & 255;
    const int ghi = win >> 4, gwi = win & 15;

    // load x tile (rows contiguous in memory, coalesced)
    #pragma unroll
    for (int t = 0; t < 16; ++t) {
        const int n = (ghi * 4 + (t >> 2)) * 64 + gwi * 4 + (t & 3);
        xt[t][tid] = x[((size_t)b * 4096 + n) * 256 + tid];
    }
    __syncthreads();

    const int h = tid >> 6, d = tid & 63;

    // qkv GEMM: thread owns cols {tid, 256+tid, 512+tid}, all 3 fused per c4
    {
        const float4* __restrict__ w0 = (const float4*)(wqkv + (size_t)(tid) * 256);
        const float4* __restrict__ w1 = (const float4*)(wqkv + (size_t)(256 + tid) * 256);
        const float4* __restrict__ w2 = (const float4*)(wqkv + (size_t)(512 + tid) * 256);
        float a0[16], a1[16], a2[16];
        const float b0 = bqkv[tid], b1 = bqkv[256 + tid], b2 = bqkv[512 + tid];
        #pragma unroll
        for (int t = 0; t < 16; ++t) { a0[t] = b0; a1[t] = b1; a2[t] = b2; }
        for (int c4 = 0; c4 < 64; ++c4) {
            const float4 wv0 = w0[c4], wv1 = w1[c4], wv2 = w2[c4];
            #pragma unroll
            for (int t = 0; t < 16; ++t) {
                const float4 xv = ((const float4*)xt[t])[c4];
                a0[t] += xv.x * wv0.x + xv.y * wv0.y + xv.z * wv0.z + xv.w * wv0.w;
                a1[t] += xv.x * wv1.x + xv.y * wv1.y + xv.z * wv1.z + xv.w * wv1.w;
                a2[t] += xv.x * wv2.x + xv.y * wv2.y + xv.z * wv2.z + xv.w * wv2.w;
            }
        }
        #pragma unroll
        for (int t = 0; t < 16; ++t) {
            qkv[0 + h][t][d] = a0[t];
            qkv[4 + h][t][d] = a1[t];
            qkv[8 + h][t][d] = a2[t];
        }
    }
    __syncthreads();

    // window attention: 64 threads, one per (head, q-token). scores + softmax
    // + PV all in registers; accumulate into xt (z = x + attn_out).
    if (tid < 64) {
        const int h2 = tid >> 4, q = tid & 15;
        float s[16];
        float m = -1e30f;
        for (int kt = 0; kt < 16; ++kt) {
            float acc = 0.f;
            #pragma unroll
            for (int c4 = 0; c4 < 16; ++c4) {
                const float4 a = ((const float4*)qkv[h2][q])[c4];
                const float4 k = ((const float4*)qkv[4 + h2][kt])[c4];
                acc += a.x * k.x + a.y * k.y + a.z * k.z + a.w * k.w;
            }
            s[kt] = acc * SCALE;
            m = fmaxf(m, s[kt]);
        }
        float l = 0.f;
        #pragma unroll
        for (int kt = 0; kt < 16; ++kt) { s[kt] = __expf(s[kt] - m); l += s[kt]; }
        const float inv = 1.f / l;
        #pragma unroll
        for (int kt = 0; kt < 16; ++kt) s[kt] *= inv;

        float4* xp = (float4*)&xt[q][h2 * 64];
        #pragma unroll
        for (int c4 = 0; c4 < 16; ++c4) {
            float4 a = xp[c4];  // residual base (x)
            #pragma unroll
            for (int kt = 0; kt < 16; ++kt) {
                const float4 vv = ((const float4*)qkv[8 + h2][kt])[c4];
                a.x += s[kt] * vv.x; a.y += s[kt] * vv.y;
                a.z += s[kt] * vv.z; a.w += s[kt] * vv.w;
            }
            xp[c4] = a;
        }
    }
    __syncthreads();

    // LayerNorm over 256 channels per token; wave wv handles 4 tokens
    {
        const int wv = tid >> 6, lane = tid & 63;
        const float4 gw = ((const float4*)gnw)[lane];
        const float4 gb = ((const float4*)gnb)[lane];
        for (int i = 0; i < 4; ++i) {
            const int t = wv * 4 + i;
            const float4 zv = ((const float4*)xt[t])[lane];
            float ssum = zv.x + zv.y + zv.z + zv.w;
            for (int off = 1; off < 64; off <<= 1) ssum += __shfl_xor(ssum, off);
            const float u = ssum * (1.f / 256.f);
            const float dx = zv.x - u, dy = zv.y - u, dz = zv.z - u, dw = zv.w - u;
            float vsum = dx * dx + dy * dy + dz * dz + dw * dw;
            for (int off = 1; off < 64; off <<= 1) vsum += __shfl_xor(vsum, off);
            const float rinv = rsqrtf(vsum * (1.f / 256.f) + LN_EPS);
            float4 y;
            y.x = gw.x * dx * rinv + gb.x;
            y.y = gw.y * dy * rinv + gb.y;
            y.z = gw.z * dz * rinv + gb.z;
            y.w = gw.w * dw * rinv + gb.w;
            ((float4*)xt[t])[lane] = y;
            const int n = (ghi * 4 + (t >> 2)) * 64 + gwi * 4 + (t & 3);
            ((float4*)(ln_out + ((size_t)b * 4096 + n) * 256))[lane] = y;
        }
    }
    __syncthreads();

    // 4x4 avg pool of LN output (window == pool region)
    {
        float ps = 0.f;
        #pragma unroll
        for (int t = 0; t < 16; ++t) ps += xt[t][tid];
        pooled[((size_t)b * 256 + win) * 256 + tid] = ps * (1.f / 16.f);
    }
}

// ---------------------------------------------------------------------------
// K2: kv = pooled @ Wkv^T + b. 256 blocks x 16 pooled rows.
// kvbuf layout: [b][seg(k=0,v=1)][head][p][d]
// ---------------------------------------------------------------------------
__global__ __launch_bounds__(256) void k_kv(
    const float* __restrict__ pooled, const float* __restrict__ wkv,
    const float* __restrict__ bkv, float* __restrict__ kvbuf)
{
    __shared__ float pt[16][256];
    const int tid = threadIdx.x;
    const int r0 = blockIdx.x * 16;               // global pooled row = b*256 + p
    #pragma unroll
    for (int t = 0; t < 16; ++t) pt[t][tid] = pooled[(size_t)(r0 + t) * 256 + tid];
    __syncthreads();

    const int b = r0 >> 8, p0 = r0 & 255;
    const int h = tid >> 6, d = tid & 63;
    for (int seg = 0; seg < 2; ++seg) {
        const int o = seg * 256 + tid;
        const float4* __restrict__ wr = (const float4*)(wkv + (size_t)o * 256);
        float acc[16];
        const float bb = bkv[o];
        #pragma unroll
        for (int t = 0; t < 16; ++t) acc[t] = bb;
        for (int c4 = 0; c4 < 64; ++c4) {
            const float4 wv = wr[c4];
            #pragma unroll
            for (int t = 0; t < 16; ++t) {
                const float4 xv = ((const float4*)pt[t])[c4];
                acc[t] += xv.x * wv.x + xv.y * wv.y + xv.z * wv.z + xv.w * wv.w;
            }
        }
        #pragma unroll
        for (int t = 0; t < 16; ++t)
            kvbuf[((((size_t)b * 2 + seg) * 4 + h) * 256 + (p0 + t)) * 64 + d] = acc[t];
    }
}

// ---------------------------------------------------------------------------
// K3: qg = ln_out @ Wq^T + b, stored head-major qg[b][h][n][d]. 4096 blocks.
// ---------------------------------------------------------------------------
__global__ __launch_bounds__(256) void k_qproj(
    const float* __restrict__ ln, const float* __restrict__ wq,
    const float* __restrict__ bq, float* __restrict__ qg)
{
    __shared__ float lt[16][256];
    const int tid = threadIdx.x;
    const size_t r0 = (size_t)blockIdx.x * 16;    // global row = b*4096 + n
    #pragma unroll
    for (int t = 0; t < 16; ++t) lt[t][tid] = ln[(r0 + t) * 256 + tid];
    __syncthreads();

    const float4* __restrict__ wr = (const float4*)(wq + (size_t)tid * 256);
    float acc[16];
    const float bb = bq[tid];
    #pragma unroll
    for (int t = 0; t < 16; ++t) acc[t] = bb;
    for (int c4 = 0; c4 < 64; ++c4) {
        const float4 wv = wr[c4];
        #pragma unroll
        for (int t = 0; t < 16; ++t) {
            const float4 xv = ((const float4*)lt[t])[c4];
            acc[t] += xv.x * wv.x + xv.y * wv.y + xv.z * wv.z + xv.w * wv.w;
        }
    }
    const int b = (int)(r0 >> 12);
    const int n0 = (int)(r0 & 4095);
    const int h = tid >> 6, d = tid & 63;
    #pragma unroll
    for (int t = 0; t < 16; ++t)
        qg[(((size_t)(b * 4 + h)) * 4096 + (n0 + t)) * 64 + d] = acc[t];
}

// ---------------------------------------------------------------------------
// K4: pooled global attention. Block = (b, h, 256-row q-tile). 1024 blocks.
// K/V staged in LDS in two 128-key chunks (64KB total). Per-thread q-row in
// registers, softmax without max-sub (scores bounded ~O(1)).
// Writes gx = attn_out + ln_out (residual).
// ---------------------------------------------------------------------------
__global__ __launch_bounds__(256) void k_glb(
    const float* __restrict__ qg, const float* __restrict__ kvbuf,
    const float* __restrict__ ln, float* __restrict__ gx)
{
    __shared__ float kt[128][64];
    __shared__ float vt[128][64];

    const int tid = threadIdx.x;
    const int blk = blockIdx.x;
    const int qt = blk & 15;
    const int bh = blk >> 4;            // b*4 + h
    const int h = bh & 3, b = bh >> 2;

    const int n = qt * 256 + tid;
    const float4* __restrict__ qrow = (const float4*)(qg + ((size_t)bh * 4096 + n) * 64);
    float4 q4[16];
    #pragma unroll
    for (int i = 0; i < 16; ++i) q4[i] = qrow[i];

    float4 acc[16];
    #pragma unroll
    for (int i = 0; i < 16; ++i) acc[i] = make_float4(0.f, 0.f, 0.f, 0.f);
    float l = 0.f;

    const float4* __restrict__ ksrc = (const float4*)(kvbuf + (((size_t)b * 2 + 0) * 4 + h) * 256 * 64);
    const float4* __restrict__ vsrc = (const float4*)(kvbuf + (((size_t)b * 2 + 1) * 4 + h) * 256 * 64);
    float4* k4 = (float4*)&kt[0][0];
    float4* v4 = (float4*)&vt[0][0];

    for (int chunk = 0; chunk < 2; ++chunk) {
        __syncthreads();
        #pragma unroll
        for (int i = 0; i < 8; ++i) {
            k4[tid + i * 256] = ksrc[chunk * 2048 + tid + i * 256];
            v4[tid + i * 256] = vsrc[chunk * 2048 + tid + i * 256];
        }
        __syncthreads();
        for (int k = 0; k < 128; ++k) {
            const float4* __restrict__ kr = (const float4*)kt[k];
            float s = 0.f;
            #pragma unroll
            for (int i = 0; i < 16; ++i) {
                const float4 kk = kr[i];
                s += q4[i].x * kk.x + q4[i].y * kk.y + q4[i].z * kk.z + q4[i].w * kk.w;
            }
            const float p = __expf(s * SCALE);
            l += p;
            const float4* __restrict__ vr = (const float4*)vt[k];
            #pragma unroll
            for (int i = 0; i < 16; ++i) {
                const float4 vv = vr[i];
                acc[i].x += p * vv.x; acc[i].y += p * vv.y;
                acc[i].z += p * vv.z; acc[i].w += p * vv.w;
            }
        }
    }

    const float inv = 1.f / l;
    const size_t obase = ((size_t)b * 4096 + n) * 256 + h * 64;
    const float4* __restrict__ lr = (const float4*)(ln + obase);
    float4* __restrict__ gr = (float4*)(gx + obase);
    #pragma unroll
    for (int i = 0; i < 16; ++i) {
        const float4 rv = lr[i];
        float4 r;
        r.x = acc[i].x * inv + rv.x;
        r.y = acc[i].y * inv + rv.y;
        r.z = acc[i].z * inv + rv.z;
        r.w = acc[i].w * inv + rv.w;
        gr[i] = r;
    }
}

// ---------------------------------------------------------------------------
// K5: out = gx @ Wproj^T + b. 4096 blocks x 16 rows, output (B,N,C).
// ---------------------------------------------------------------------------
__global__ __launch_bounds__(256) void k_proj(
    const float* __restrict__ gxin, const float* __restrict__ wp,
    const float* __restrict__ bp, float* __restrict__ out)
{
    __shared__ float lt[16][256];
    const int tid = threadIdx.x;
    const size_t r0 = (size_t)blockIdx.x * 16;
    #pragma unroll
    for (int t = 0; t < 16; ++t) lt[t][tid] = gxin[(r0 + t) * 256 + tid];
    __syncthreads();

    const float4* __restrict__ wr = (const float4*)(wp + (size_t)tid * 256);
    float acc[16];
    const float bb = bp[tid];
    #pragma unroll
    for (int t = 0; t < 16; ++t) acc[t] = bb;
    for (int c4 = 0; c4 < 64; ++c4) {
        const float4 wv = wr[c4];
        #pragma unroll
        for (int t = 0; t < 16; ++t) {
            const float4 xv = ((const float4*)lt[t])[c4];
            acc[t] += xv.x * wv.x + xv.y * wv.y + xv.z * wv.z + xv.w * wv.w;
        }
    }
    #pragma unroll
    for (int t = 0; t < 16; ++t) out[(r0 + t) * 256 + tid] = acc[t];
}

// ---------------------------------------------------------------------------
extern "C" void kernel_launch(void* const* d_in, const int* in_sizes, int n_in,
                              void* d_out, int out_size, void* d_ws, size_t ws_size,
                              hipStream_t stream)
{
    (void)in_sizes; (void)n_in; (void)out_size; (void)ws_size;
    const float* x     = (const float*)d_in[0];
    const float* wqkv  = (const float*)d_in[1];
    const float* bqkv  = (const float*)d_in[2];
    const float* wq    = (const float*)d_in[3];
    const float* bq    = (const float*)d_in[4];
    const float* wkv   = (const float*)d_in[5];
    const float* bkv   = (const float*)d_in[6];
    const float* wproj = (const float*)d_in[7];
    const float* bproj = (const float*)d_in[8];
    const float* gnw   = (const float*)d_in[9];
    const float* gnb   = (const float*)d_in[10];
    float* out = (float*)d_out;

    // workspace carve-up (floats): ln_out 16.78M, qg 16.78M, gx 16.78M,
    // pooled 1.05M, kv 2.10M  -> ~214 MB total
    float* ws     = (float*)d_ws;
    float* ln_out = ws;
    float* qg     = ws + (size_t)16777216;
    float* gx     = ws + (size_t)33554432;
    float* pooled = ws + (size_t)50331648;
    float* kvbuf  = ws + (size_t)51380224;

    k_win  <<<dim3(4096), dim3(256), 0, stream>>>(x, wqkv, bqkv, gnw, gnb, ln_out, pooled);
    k_kv   <<<dim3(256),  dim3(256), 0, stream>>>(pooled, wkv, bkv, kvbuf);
    k_qproj<<<dim3(4096), dim3(256), 0, stream>>>(ln_out, wq, bq, qg);
    k_glb  <<<dim3(1024), dim3(256), 0, stream>>>(qg, kvbuf, ln_out, gx);
    k_proj <<<dim3(4096), dim3(256), 0, stream>>>(gx, wproj, bproj, out);
}

// Round 2
// 669.240 us; speedup vs baseline: 2.8003x; 2.8003x over previous
//
#include <hip/hip_runtime.h>
#include <cstddef>

#define SCALE 0.125f
#define LN_EPS 1e-6f

typedef __attribute__((ext_vector_type(8))) short bf16x8;
typedef __attribute__((ext_vector_type(4))) float f32x4;

__device__ __forceinline__ unsigned short f2bf(float f) {
    unsigned u = __float_as_uint(f);
    return (unsigned short)((u + 0x7FFFu + ((u >> 16) & 1u)) >> 16);
}
__device__ __forceinline__ unsigned pack2(float a, float b) {
    return (unsigned)f2bf(a) | ((unsigned)f2bf(b) << 16);
}
__device__ __forceinline__ float bflo(unsigned v) { return __uint_as_float(v << 16); }
__device__ __forceinline__ float bfhi(unsigned v) { return __uint_as_float(v & 0xFFFF0000u); }
__device__ __forceinline__ float bf2f(short s) { return __uint_as_float(((unsigned)(unsigned short)s) << 16); }

// ---------------------------------------------------------------------------
// Cast all 4 weight matrices f32 -> bf16 into wb.
// Segments (short offsets): wqkv@0 (196608), wq@196608 (65536),
// wkv@262144 (131072), wproj@393216 (65536). 2048 elems per block.
// ---------------------------------------------------------------------------
__global__ __launch_bounds__(256) void k_castw(
    const float* __restrict__ wqkv, const float* __restrict__ wq,
    const float* __restrict__ wkv, const float* __restrict__ wproj,
    short* __restrict__ wb)
{
    const int blk = blockIdx.x;
    const float* src; size_t so, doff;
    if (blk < 96)       { src = wqkv;  so = (size_t)blk * 2048;         doff = 0; }
    else if (blk < 128) { src = wq;    so = (size_t)(blk - 96) * 2048;  doff = 196608; }
    else if (blk < 192) { src = wkv;   so = (size_t)(blk - 128) * 2048; doff = 262144; }
    else                { src = wproj; so = (size_t)(blk - 192) * 2048; doff = 393216; }
    const size_t idx = so + (size_t)threadIdx.x * 8;
    const float4 f0 = *(const float4*)(src + idx);
    const float4 f1 = *(const float4*)(src + idx + 4);
    uint4 o;
    o.x = pack2(f0.x, f0.y); o.y = pack2(f0.z, f0.w);
    o.z = pack2(f1.x, f1.y); o.w = pack2(f1.z, f1.w);
    *(uint4*)(wb + doff + idx) = o;
}

// ---------------------------------------------------------------------------
// MFMA GEMM: C[M][ldc] = A[M][256] @ Bw[N][256]^T + bias.
// Tile 128x128, K=256 in 2 chunks of 128. 4 waves, each 64x64 (acc[4][4]).
// LDS 64KB, XOR-swizzled (elem ^= (row&7)<<3) for conflict-free ds_read_b128.
// SRCF32: A is f32 (cast during staging) else bf16. OUTBF16: C bf16 else f32.
// ---------------------------------------------------------------------------
template<int SRCF32, int OUTBF16>
__global__ __launch_bounds__(256) void k_gemm(
    const void* __restrict__ Asrc, const short* __restrict__ Bw,
    const float* __restrict__ bias, void* __restrict__ Cdst,
    int ldc, int nbn)
{
    __shared__ short As[128 * 128];
    __shared__ short Bs[128 * 128];

    const int tid = threadIdx.x;
    // XCD-aware swizzle (grid always divisible by 8)
    const int q8 = gridDim.x >> 3;
    const int bid = (blockIdx.x & 7) * q8 + (blockIdx.x >> 3);
    const int bm = bid / nbn, bn = bid % nbn;
    const size_t m0 = (size_t)bm * 128, n0 = (size_t)bn * 128;
    const int wid = tid >> 6, lane = tid & 63;
    const int wr = wid >> 1, wc = wid & 1;
    const int g = lane >> 4, r = lane & 15;

    f32x4 acc[4][4];
    #pragma unroll
    for (int mi = 0; mi < 4; ++mi)
        #pragma unroll
        for (int nj = 0; nj < 4; ++nj) acc[mi][nj] = (f32x4)0.f;

    for (int kc = 0; kc < 2; ++kc) {
        if (kc) __syncthreads();
        // ---- stage A and B K-chunk into swizzled LDS ----
        #pragma unroll
        for (int i = 0; i < 8; ++i) {
            const int c = i * 256 + tid;
            const int row = c >> 4, col = c & 15;
            const int lidx = row * 128 + ((col * 8) ^ ((row & 7) << 3));
            if (SRCF32) {
                const float* ap = (const float*)Asrc + (m0 + row) * 256 + kc * 128 + col * 8;
                const float4 f0 = *(const float4*)ap;
                const float4 f1 = *(const float4*)(ap + 4);
                uint4 o;
                o.x = pack2(f0.x, f0.y); o.y = pack2(f0.z, f0.w);
                o.z = pack2(f1.x, f1.y); o.w = pack2(f1.z, f1.w);
                *(uint4*)(&As[lidx]) = o;
            } else {
                const short* ap = (const short*)Asrc + (m0 + row) * 256 + kc * 128 + col * 8;
                *(uint4*)(&As[lidx]) = *(const uint4*)ap;
            }
            const short* bp = Bw + (n0 + row) * 256 + kc * 128 + col * 8;
            *(uint4*)(&Bs[lidx]) = *(const uint4*)bp;
        }
        __syncthreads();
        // ---- 4 K-steps of 32 ----
        #pragma unroll
        for (int ks = 0; ks < 4; ++ks) {
            const int ke = ks * 32 + g * 8;
            bf16x8 a[4], b[4];
            #pragma unroll
            for (int mi = 0; mi < 4; ++mi) {
                const int row = wr * 64 + mi * 16 + r;
                a[mi] = *(const bf16x8*)(&As[row * 128 + (ke ^ ((row & 7) << 3))]);
            }
            #pragma unroll
            for (int nj = 0; nj < 4; ++nj) {
                const int row = wc * 64 + nj * 16 + r;
                b[nj] = *(const bf16x8*)(&Bs[row * 128 + (ke ^ ((row & 7) << 3))]);
            }
            #pragma unroll
            for (int mi = 0; mi < 4; ++mi)
                #pragma unroll
                for (int nj = 0; nj < 4; ++nj)
                    acc[mi][nj] = __builtin_amdgcn_mfma_f32_16x16x32_bf16(
                        a[mi], b[nj], acc[mi][nj], 0, 0, 0);
        }
    }

    // ---- epilogue: bias add, store ----
    #pragma unroll
    for (int nj = 0; nj < 4; ++nj) {
        const size_t col = n0 + wc * 64 + nj * 16 + r;
        const float bv = bias[col];
        #pragma unroll
        for (int mi = 0; mi < 4; ++mi) {
            const size_t row = m0 + wr * 64 + mi * 16 + g * 4;
            #pragma unroll
            for (int e = 0; e < 4; ++e) {
                const float v = acc[mi][nj][e] + bv;
                if (OUTBF16) ((short*)Cdst)[(row + e) * ldc + col] = (short)f2bf(v);
                else         ((float*)Cdst)[(row + e) * ldc + col] = v;
            }
        }
    }
}

// ---------------------------------------------------------------------------
// Window attention + residual + LN + pool. Block per (b, 4x4 window).
// Reads qkvb[n][768] bf16 (cols: seg*256 + h*64 + d), x f32 for residual.
// All 256 threads active in scores (h,q,r->4kt) and PV (h,d) phases.
// LDS: qk[16][772] f32 (q-region reused for z/y) + sm[4][16][16].
// ---------------------------------------------------------------------------
__global__ __launch_bounds__(256) void k_win2(
    const short* __restrict__ qkvb, const float* __restrict__ x,
    const float* __restrict__ gnw, const float* __restrict__ gnb,
    short* __restrict__ lnb, short* __restrict__ pooledb)
{
    __shared__ float qk[16][772];
    __shared__ float sm[4][16][16];

    const int tid = threadIdx.x;
    const int blk = blockIdx.x;
    const int b = blk >> 8, win = blk & 255;
    const int ghi = win >> 4, gwi = win & 15;
    const size_t nb = (size_t)b * 4096;

    // ---- stage qkv tile (16 tokens x 768) bf16 -> f32 LDS ----
    {
        const int t = tid >> 4, l16 = tid & 15;
        const int n = (ghi * 4 + (t >> 2)) * 64 + gwi * 4 + (t & 3);
        const short* gp = qkvb + (nb + n) * 768;
        #pragma unroll
        for (int j = 0; j < 6; ++j) {
            const int c16 = l16 + j * 16;
            const uint4 u = *(const uint4*)(gp + c16 * 8);
            float4 a, c;
            a.x = bflo(u.x); a.y = bfhi(u.x); a.z = bflo(u.y); a.w = bfhi(u.y);
            c.x = bflo(u.z); c.y = bfhi(u.z); c.z = bflo(u.w); c.w = bfhi(u.w);
            *(float4*)&qk[t][c16 * 8] = a;
            *(float4*)&qk[t][c16 * 8 + 4] = c;
        }
    }
    __syncthreads();

    // ---- scores: thread (h, q, r) computes kt = r, r+4, r+8, r+12 ... (i*4+r) ----
    {
        const int h = tid >> 6, q = (tid >> 2) & 15, r = tid & 3;
        float4 qv[16];
        const float4* qrow = (const float4*)&qk[q][h * 64];
        #pragma unroll
        for (int i = 0; i < 16; ++i) qv[i] = qrow[i];
        #pragma unroll
        for (int i = 0; i < 4; ++i) {
            const int kt = i * 4 + r;
            const float4* krow = (const float4*)&qk[kt][256 + h * 64];
            float acc = 0.f;
            #pragma unroll
            for (int c4 = 0; c4 < 16; ++c4) {
                const float4 kk = krow[c4];
                acc += qv[c4].x * kk.x + qv[c4].y * kk.y + qv[c4].z * kk.z + qv[c4].w * kk.w;
            }
            sm[h][q][kt] = acc * SCALE;
        }
    }
    __syncthreads();

    // ---- softmax over 16 keys, thread (h,q), tid<64 ----
    if (tid < 64) {
        const int h = tid >> 4, q = tid & 15;
        float4* sp = (float4*)&sm[h][q][0];
        float4 s0 = sp[0], s1 = sp[1], s2 = sp[2], s3 = sp[3];
        float m = fmaxf(fmaxf(fmaxf(fmaxf(s0.x, s0.y), fmaxf(s0.z, s0.w)),
                              fmaxf(fmaxf(s1.x, s1.y), fmaxf(s1.z, s1.w))),
                        fmaxf(fmaxf(fmaxf(s2.x, s2.y), fmaxf(s2.z, s2.w)),
                              fmaxf(fmaxf(s3.x, s3.y), fmaxf(s3.z, s3.w))));
        s0.x = __expf(s0.x - m); s0.y = __expf(s0.y - m); s0.z = __expf(s0.z - m); s0.w = __expf(s0.w - m);
        s1.x = __expf(s1.x - m); s1.y = __expf(s1.y - m); s1.z = __expf(s1.z - m); s1.w = __expf(s1.w - m);
        s2.x = __expf(s2.x - m); s2.y = __expf(s2.y - m); s2.z = __expf(s2.z - m); s2.w = __expf(s2.w - m);
        s3.x = __expf(s3.x - m); s3.y = __expf(s3.y - m); s3.z = __expf(s3.z - m); s3.w = __expf(s3.w - m);
        const float l = s0.x + s0.y + s0.z + s0.w + s1.x + s1.y + s1.z + s1.w
                      + s2.x + s2.y + s2.z + s2.w + s3.x + s3.y + s3.z + s3.w;
        const float inv = 1.f / l;
        s0.x *= inv; s0.y *= inv; s0.z *= inv; s0.w *= inv;
        s1.x *= inv; s1.y *= inv; s1.z *= inv; s1.w *= inv;
        s2.x *= inv; s2.y *= inv; s2.z *= inv; s2.w *= inv;
        s3.x *= inv; s3.y *= inv; s3.z *= inv; s3.w *= inv;
        sp[0] = s0; sp[1] = s1; sp[2] = s2; sp[3] = s3;
    }
    __syncthreads();

    // ---- PV + residual: thread (h,d); z written into qk[q][0..255] ----
    {
        const int h = tid >> 6, d = tid & 63;
        float v[16];
        #pragma unroll
        for (int kt = 0; kt < 16; ++kt) v[kt] = qk[kt][512 + h * 64 + d];
        #pragma unroll
        for (int q = 0; q < 16; ++q) {
            const float4* sp = (const float4*)&sm[h][q][0];
            const float4 a0 = sp[0], a1 = sp[1], a2 = sp[2], a3 = sp[3];
            float o = a0.x * v[0] + a0.y * v[1] + a0.z * v[2] + a0.w * v[3]
                    + a1.x * v[4] + a1.y * v[5] + a1.z * v[6] + a1.w * v[7]
                    + a2.x * v[8] + a2.y * v[9] + a2.z * v[10] + a2.w * v[11]
                    + a3.x * v[12] + a3.y * v[13] + a3.z * v[14] + a3.w * v[15];
            const int n = (ghi * 4 + (q >> 2)) * 64 + gwi * 4 + (q & 3);
            const float xr = x[(nb + n) * 256 + h * 64 + d];
            qk[q][h * 64 + d] = o + xr;
        }
    }
    __syncthreads();

    // ---- LayerNorm per token (wave handles 4 tokens), write lnb + back to LDS ----
    {
        const int wv = tid >> 6, lane = tid & 63;
        const float4 gw = ((const float4*)gnw)[lane];
        const float4 gb = ((const float4*)gnb)[lane];
        #pragma unroll
        for (int i = 0; i < 4; ++i) {
            const int t = wv * 4 + i;
            const float4 zv = *(const float4*)&qk[t][lane * 4];
            float ssum = zv.x + zv.y + zv.z + zv.w;
            for (int off = 1; off < 64; off <<= 1) ssum += __shfl_xor(ssum, off);
            const float u = ssum * (1.f / 256.f);
            const float dx = zv.x - u, dy = zv.y - u, dz = zv.z - u, dw = zv.w - u;
            float vsum = dx * dx + dy * dy + dz * dz + dw * dw;
            for (int off = 1; off < 64; off <<= 1) vsum += __shfl_xor(vsum, off);
            const float rinv = rsqrtf(vsum * (1.f / 256.f) + LN_EPS);
            float4 y;
            y.x = gw.x * dx * rinv + gb.x;
            y.y = gw.y * dy * rinv + gb.y;
            y.z = gw.z * dz * rinv + gb.z;
            y.w = gw.w * dw * rinv + gb.w;
            *(float4*)&qk[t][lane * 4] = y;
            const int n = (ghi * 4 + (t >> 2)) * 64 + gwi * 4 + (t & 3);
            short4 sv;
            sv.x = (short)f2bf(y.x); sv.y = (short)f2bf(y.y);
            sv.z = (short)f2bf(y.z); sv.w = (short)f2bf(y.w);
            *(short4*)(lnb + (nb + n) * 256 + lane * 4) = sv;
        }
    }
    __syncthreads();

    // ---- 4x4 avg pool of LN output ----
    {
        float ps = 0.f;
        #pragma unroll
        for (int t = 0; t < 16; ++t) ps += qk[t][tid];
        pooledb[((size_t)b * 256 + win) * 256 + tid] = (short)f2bf(ps * (1.f / 16.f));
    }
}

// ---------------------------------------------------------------------------
// Pooled global attention (bf16 in/out). Block = (b, h, 256-row q-tile).
// qgb[n][256] (col h*64+d), kvb[b*256+p][512] (K at h*64+d, V at 256+h*64+d),
// lnb residual, gxb output (bf16).
// ---------------------------------------------------------------------------
__global__ __launch_bounds__(256) void k_glb(
    const short* __restrict__ qgb, const short* __restrict__ kvb,
    const short* __restrict__ lnb, short* __restrict__ gxb)
{
    __shared__ float kt[128][64];
    __shared__ float vt[128][64];

    const int tid = threadIdx.x;
    const int blk = blockIdx.x;
    const int qt = blk & 15;
    const int bh = blk >> 4;
    const int h = bh & 3, b = bh >> 2;

    const int n = qt * 256 + tid;
    const size_t qoff = ((size_t)b * 4096 + n) * 256 + h * 64;

    float4 q4[16];
    {
        const uint4* qp = (const uint4*)(qgb + qoff);
        #pragma unroll
        for (int i = 0; i < 8; ++i) {
            const uint4 u = qp[i];
            float4 a, c;
            a.x = bflo(u.x); a.y = bfhi(u.x); a.z = bflo(u.y); a.w = bfhi(u.y);
            c.x = bflo(u.z); c.y = bfhi(u.z); c.z = bflo(u.w); c.w = bfhi(u.w);
            q4[2 * i] = a; q4[2 * i + 1] = c;
        }
    }

    float4 acc[16];
    #pragma unroll
    for (int i = 0; i < 16; ++i) acc[i] = make_float4(0.f, 0.f, 0.f, 0.f);
    float l = 0.f;

    const short* kvbase = kvb + (size_t)b * 256 * 512;

    for (int chunk = 0; chunk < 2; ++chunk) {
        __syncthreads();
        // stage 128 keys of K and V (bf16 -> f32)
        #pragma unroll
        for (int i = 0; i < 4; ++i) {
            const int c = i * 256 + tid;
            const int krow = c >> 3, c8 = c & 7;
            const short* kp = kvbase + (size_t)(chunk * 128 + krow) * 512 + h * 64 + c8 * 8;
            const uint4 uk = *(const uint4*)kp;
            const uint4 uv = *(const uint4*)(kp + 256);
            float4 a, c4v;
            a.x = bflo(uk.x); a.y = bfhi(uk.x); a.z = bflo(uk.y); a.w = bfhi(uk.y);
            c4v.x = bflo(uk.z); c4v.y = bfhi(uk.z); c4v.z = bflo(uk.w); c4v.w = bfhi(uk.w);
            *(float4*)&kt[krow][c8 * 8] = a;
            *(float4*)&kt[krow][c8 * 8 + 4] = c4v;
            a.x = bflo(uv.x); a.y = bfhi(uv.x); a.z = bflo(uv.y); a.w = bfhi(uv.y);
            c4v.x = bflo(uv.z); c4v.y = bfhi(uv.z); c4v.z = bflo(uv.w); c4v.w = bfhi(uv.w);
            *(float4*)&vt[krow][c8 * 8] = a;
            *(float4*)&vt[krow][c8 * 8 + 4] = c4v;
        }
        __syncthreads();
        for (int k = 0; k < 128; ++k) {
            const float4* kr = (const float4*)kt[k];
            float s = 0.f;
            #pragma unroll
            for (int i = 0; i < 16; ++i) {
                const float4 kk = kr[i];
                s += q4[i].x * kk.x + q4[i].y * kk.y + q4[i].z * kk.z + q4[i].w * kk.w;
            }
            const float p = __expf(s * SCALE);
            l += p;
            const float4* vr = (const float4*)vt[k];
            #pragma unroll
            for (int i = 0; i < 16; ++i) {
                const float4 vv = vr[i];
                acc[i].x += p * vv.x; acc[i].y += p * vv.y;
                acc[i].z += p * vv.z; acc[i].w += p * vv.w;
            }
        }
    }

    const float inv = 1.f / l;
    const short* lp = lnb + qoff;
    short* gp = gxb + qoff;
    #pragma unroll
    for (int i = 0; i < 16; ++i) {
        const short4 lv = *(const short4*)(lp + i * 4);
        short4 sv;
        sv.x = (short)f2bf(acc[i].x * inv + bf2f(lv.x));
        sv.y = (short)f2bf(acc[i].y * inv + bf2f(lv.y));
        sv.z = (short)f2bf(acc[i].z * inv + bf2f(lv.z));
        sv.w = (short)f2bf(acc[i].w * inv + bf2f(lv.w));
        *(short4*)(gp + i * 4) = sv;
    }
}

// ---------------------------------------------------------------------------
extern "C" void kernel_launch(void* const* d_in, const int* in_sizes, int n_in,
                              void* d_out, int out_size, void* d_ws, size_t ws_size,
                              hipStream_t stream)
{
    (void)in_sizes; (void)n_in; (void)out_size; (void)ws_size;
    const float* x     = (const float*)d_in[0];
    const float* wqkv  = (const float*)d_in[1];
    const float* bqkv  = (const float*)d_in[2];
    const float* wq    = (const float*)d_in[3];
    const float* bq    = (const float*)d_in[4];
    const float* wkv   = (const float*)d_in[5];
    const float* bkv   = (const float*)d_in[6];
    const float* wproj = (const float*)d_in[7];
    const float* bproj = (const float*)d_in[8];
    const float* gnw   = (const float*)d_in[9];
    const float* gnb   = (const float*)d_in[10];
    float* out = (float*)d_out;

    char* wsb = (char*)d_ws;
    short* wb      = (short*)(wsb + 0);            // 458752 bf16 (cast weights)
    short* qkvb    = (short*)(wsb + 1048576);      // 65536 x 768
    short* lnb     = (short*)(wsb + 101711872);    // 65536 x 256
    short* qgb     = (short*)(wsb + 135266304);    // 65536 x 256
    short* kvb     = (short*)(wsb + 168820736);    // 4096 x 512
    short* pooledb = (short*)(wsb + 173015040);    // 4096 x 256
    short* gxb     = (short*)(wsb + 175112192);    // 65536 x 256

    k_castw<<<dim3(224), dim3(256), 0, stream>>>(wqkv, wq, wkv, wproj, wb);
    // qkv = x @ Wqkv^T + b            (65536 x 768, K=256)
    k_gemm<1, 1><<<dim3(3072), dim3(256), 0, stream>>>(x, wb, bqkv, qkvb, 768, 6);
    // window attention + LN + pool
    k_win2<<<dim3(4096), dim3(256), 0, stream>>>(qkvb, x, gnw, gnb, lnb, pooledb);
    // qg = ln @ Wq^T + b              (65536 x 256)
    k_gemm<0, 1><<<dim3(1024), dim3(256), 0, stream>>>(lnb, wb + 196608, bq, qgb, 256, 2);
    // kv = pooled @ Wkv^T + b         (4096 x 512)
    k_gemm<0, 1><<<dim3(128), dim3(256), 0, stream>>>(pooledb, wb + 262144, bkv, kvb, 512, 4);
    // pooled global attention + residual
    k_glb<<<dim3(1024), dim3(256), 0, stream>>>(qgb, kvb, lnb, gxb);
    // out = gx @ Wproj^T + b          (65536 x 256, f32 out)
    k_gemm<0, 0><<<dim3(1024), dim3(256), 0, stream>>>(gxb, wb + 393216, bproj, out, 256, 2);
}

// Round 3
// 263.063 us; speedup vs baseline: 7.1241x; 2.5440x over previous
//
#include <hip/hip_runtime.h>
#include <cstddef>

#define SCALE 0.125f
#define LN_EPS 1e-6f

typedef __attribute__((ext_vector_type(8))) short bf16x8;
typedef __attribute__((ext_vector_type(4))) float f32x4;

__device__ __forceinline__ unsigned short f2bf(float f) {
    unsigned u = __float_as_uint(f);
    return (unsigned short)((u + 0x7FFFu + ((u >> 16) & 1u)) >> 16);
}
__device__ __forceinline__ unsigned pack2(float a, float b) {
    return (unsigned)f2bf(a) | ((unsigned)f2bf(b) << 16);
}
__device__ __forceinline__ float bflo(unsigned v) { return __uint_as_float(v << 16); }
__device__ __forceinline__ float bfhi(unsigned v) { return __uint_as_float(v & 0xFFFF0000u); }
__device__ __forceinline__ float bf2f(short s) { return __uint_as_float(((unsigned)(unsigned short)s) << 16); }

// ---------------------------------------------------------------------------
// Cast all 4 weight matrices f32 -> bf16 into wb.
// ---------------------------------------------------------------------------
__global__ __launch_bounds__(256) void k_castw(
    const float* __restrict__ wqkv, const float* __restrict__ wq,
    const float* __restrict__ wkv, const float* __restrict__ wproj,
    short* __restrict__ wb)
{
    const int blk = blockIdx.x;
    const float* src; size_t so, doff;
    if (blk < 96)       { src = wqkv;  so = (size_t)blk * 2048;         doff = 0; }
    else if (blk < 128) { src = wq;    so = (size_t)(blk - 96) * 2048;  doff = 196608; }
    else if (blk < 192) { src = wkv;   so = (size_t)(blk - 128) * 2048; doff = 262144; }
    else                { src = wproj; so = (size_t)(blk - 192) * 2048; doff = 393216; }
    const size_t idx = so + (size_t)threadIdx.x * 8;
    const float4 f0 = *(const float4*)(src + idx);
    const float4 f1 = *(const float4*)(src + idx + 4);
    uint4 o;
    o.x = pack2(f0.x, f0.y); o.y = pack2(f0.z, f0.w);
    o.z = pack2(f1.x, f1.y); o.w = pack2(f1.z, f1.w);
    *(uint4*)(wb + doff + idx) = o;
}

// ---------------------------------------------------------------------------
// MFMA GEMM: C[M][ldc] = A[M][256] @ Bw[N][256]^T + bias.
// Tile 128x128, K=256 in 2 chunks of 128. 4 waves, each 64x64 (acc[4][4]).
// SRCF32: A is f32 (cast during staging) else bf16.
// OUTMODE: 0 = f32 linear, 1 = bf16 linear, 2 = kv-split:
//   cols 0..255  -> kb[row*256+col] bf16             (K, row-major)
//   cols 256..511-> vtb[((b*4+h)*64+d)*256 + p] bf16 (V transposed per (b,h))
// ---------------------------------------------------------------------------
template<int SRCF32, int OUTMODE>
__global__ __launch_bounds__(256) void k_gemm(
    const void* __restrict__ Asrc, const short* __restrict__ Bw,
    const float* __restrict__ bias, void* __restrict__ Cdst,
    short* __restrict__ Vdst, int ldc, int nbn)
{
    __shared__ short As[128 * 128];
    __shared__ short Bs[128 * 128];

    const int tid = threadIdx.x;
    const int q8 = gridDim.x >> 3;
    const int bid = (blockIdx.x & 7) * q8 + (blockIdx.x >> 3);
    const int bm = bid / nbn, bn = bid % nbn;
    const size_t m0 = (size_t)bm * 128, n0 = (size_t)bn * 128;
    const int wid = tid >> 6, lane = tid & 63;
    const int wr = wid >> 1, wc = wid & 1;
    const int g = lane >> 4, r = lane & 15;

    f32x4 acc[4][4];
    #pragma unroll
    for (int mi = 0; mi < 4; ++mi)
        #pragma unroll
        for (int nj = 0; nj < 4; ++nj) acc[mi][nj] = (f32x4)0.f;

    for (int kc = 0; kc < 2; ++kc) {
        if (kc) __syncthreads();
        #pragma unroll
        for (int i = 0; i < 8; ++i) {
            const int c = i * 256 + tid;
            const int row = c >> 4, col = c & 15;
            const int lidx = row * 128 + ((col * 8) ^ ((row & 7) << 3));
            if (SRCF32) {
                const float* ap = (const float*)Asrc + (m0 + row) * 256 + kc * 128 + col * 8;
                const float4 f0 = *(const float4*)ap;
                const float4 f1 = *(const float4*)(ap + 4);
                uint4 o;
                o.x = pack2(f0.x, f0.y); o.y = pack2(f0.z, f0.w);
                o.z = pack2(f1.x, f1.y); o.w = pack2(f1.z, f1.w);
                *(uint4*)(&As[lidx]) = o;
            } else {
                const short* ap = (const short*)Asrc + (m0 + row) * 256 + kc * 128 + col * 8;
                *(uint4*)(&As[lidx]) = *(const uint4*)ap;
            }
            const short* bp = Bw + (n0 + row) * 256 + kc * 128 + col * 8;
            *(uint4*)(&Bs[lidx]) = *(const uint4*)bp;
        }
        __syncthreads();
        #pragma unroll
        for (int ks = 0; ks < 4; ++ks) {
            const int ke = ks * 32 + g * 8;
            bf16x8 a[4], b[4];
            #pragma unroll
            for (int mi = 0; mi < 4; ++mi) {
                const int row = wr * 64 + mi * 16 + r;
                a[mi] = *(const bf16x8*)(&As[row * 128 + (ke ^ ((row & 7) << 3))]);
            }
            #pragma unroll
            for (int nj = 0; nj < 4; ++nj) {
                const int row = wc * 64 + nj * 16 + r;
                b[nj] = *(const bf16x8*)(&Bs[row * 128 + (ke ^ ((row & 7) << 3))]);
            }
            #pragma unroll
            for (int mi = 0; mi < 4; ++mi)
                #pragma unroll
                for (int nj = 0; nj < 4; ++nj)
                    acc[mi][nj] = __builtin_amdgcn_mfma_f32_16x16x32_bf16(
                        a[mi], b[nj], acc[mi][nj], 0, 0, 0);
        }
    }

    #pragma unroll
    for (int nj = 0; nj < 4; ++nj) {
        const size_t col = n0 + wc * 64 + nj * 16 + r;
        const float bv = bias[col];
        #pragma unroll
        for (int mi = 0; mi < 4; ++mi) {
            const size_t row = m0 + wr * 64 + mi * 16 + g * 4;
            #pragma unroll
            for (int e = 0; e < 4; ++e) {
                const float v = acc[mi][nj][e] + bv;
                const size_t rr = row + e;
                if (OUTMODE == 0) ((float*)Cdst)[rr * ldc + col] = v;
                else if (OUTMODE == 1) ((short*)Cdst)[rr * ldc + col] = (short)f2bf(v);
                else {
                    const int colk = (int)col - 256;
                    if (colk < 0) ((short*)Cdst)[rr * 256 + col] = (short)f2bf(v);
                    else {
                        const int hh = colk >> 6, dd = colk & 63;
                        Vdst[((((rr >> 8) * 4 + hh) * 64 + dd) << 8) + (rr & 255)] = (short)f2bf(v);
                    }
                }
            }
        }
    }
}

// ---------------------------------------------------------------------------
// Window attention + residual + LN + pool (unchanged from round 2).
// ---------------------------------------------------------------------------
__global__ __launch_bounds__(256) void k_win2(
    const short* __restrict__ qkvb, const float* __restrict__ x,
    const float* __restrict__ gnw, const float* __restrict__ gnb,
    short* __restrict__ lnb, short* __restrict__ pooledb)
{
    __shared__ float qk[16][772];
    __shared__ float sm[4][16][16];

    const int tid = threadIdx.x;
    const int blk = blockIdx.x;
    const int b = blk >> 8, win = blk & 255;
    const int ghi = win >> 4, gwi = win & 15;
    const size_t nb = (size_t)b * 4096;

    {
        const int t = tid >> 4, l16 = tid & 15;
        const int n = (ghi * 4 + (t >> 2)) * 64 + gwi * 4 + (t & 3);
        const short* gp = qkvb + (nb + n) * 768;
        #pragma unroll
        for (int j = 0; j < 6; ++j) {
            const int c16 = l16 + j * 16;
            const uint4 u = *(const uint4*)(gp + c16 * 8);
            float4 a, c;
            a.x = bflo(u.x); a.y = bfhi(u.x); a.z = bflo(u.y); a.w = bfhi(u.y);
            c.x = bflo(u.z); c.y = bfhi(u.z); c.z = bflo(u.w); c.w = bfhi(u.w);
            *(float4*)&qk[t][c16 * 8] = a;
            *(float4*)&qk[t][c16 * 8 + 4] = c;
        }
    }
    __syncthreads();

    {
        const int h = tid >> 6, q = (tid >> 2) & 15, r = tid & 3;
        float4 qv[16];
        const float4* qrow = (const float4*)&qk[q][h * 64];
        #pragma unroll
        for (int i = 0; i < 16; ++i) qv[i] = qrow[i];
        #pragma unroll
        for (int i = 0; i < 4; ++i) {
            const int kt = i * 4 + r;
            const float4* krow = (const float4*)&qk[kt][256 + h * 64];
            float acc = 0.f;
            #pragma unroll
            for (int c4 = 0; c4 < 16; ++c4) {
                const float4 kk = krow[c4];
                acc += qv[c4].x * kk.x + qv[c4].y * kk.y + qv[c4].z * kk.z + qv[c4].w * kk.w;
            }
            sm[h][q][kt] = acc * SCALE;
        }
    }
    __syncthreads();

    if (tid < 64) {
        const int h = tid >> 4, q = tid & 15;
        float4* sp = (float4*)&sm[h][q][0];
        float4 s0 = sp[0], s1 = sp[1], s2 = sp[2], s3 = sp[3];
        float m = fmaxf(fmaxf(fmaxf(fmaxf(s0.x, s0.y), fmaxf(s0.z, s0.w)),
                              fmaxf(fmaxf(s1.x, s1.y), fmaxf(s1.z, s1.w))),
                        fmaxf(fmaxf(fmaxf(s2.x, s2.y), fmaxf(s2.z, s2.w)),
                              fmaxf(fmaxf(s3.x, s3.y), fmaxf(s3.z, s3.w))));
        s0.x = __expf(s0.x - m); s0.y = __expf(s0.y - m); s0.z = __expf(s0.z - m); s0.w = __expf(s0.w - m);
        s1.x = __expf(s1.x - m); s1.y = __expf(s1.y - m); s1.z = __expf(s1.z - m); s1.w = __expf(s1.w - m);
        s2.x = __expf(s2.x - m); s2.y = __expf(s2.y - m); s2.z = __expf(s2.z - m); s2.w = __expf(s2.w - m);
        s3.x = __expf(s3.x - m); s3.y = __expf(s3.y - m); s3.z = __expf(s3.z - m); s3.w = __expf(s3.w - m);
        const float l = s0.x + s0.y + s0.z + s0.w + s1.x + s1.y + s1.z + s1.w
                      + s2.x + s2.y + s2.z + s2.w + s3.x + s3.y + s3.z + s3.w;
        const float inv = 1.f / l;
        s0.x *= inv; s0.y *= inv; s0.z *= inv; s0.w *= inv;
        s1.x *= inv; s1.y *= inv; s1.z *= inv; s1.w *= inv;
        s2.x *= inv; s2.y *= inv; s2.z *= inv; s2.w *= inv;
        s3.x *= inv; s3.y *= inv; s3.z *= inv; s3.w *= inv;
        sp[0] = s0; sp[1] = s1; sp[2] = s2; sp[3] = s3;
    }
    __syncthreads();

    {
        const int h = tid >> 6, d = tid & 63;
        float v[16];
        #pragma unroll
        for (int kt = 0; kt < 16; ++kt) v[kt] = qk[kt][512 + h * 64 + d];
        #pragma unroll
        for (int q = 0; q < 16; ++q) {
            const float4* sp = (const float4*)&sm[h][q][0];
            const float4 a0 = sp[0], a1 = sp[1], a2 = sp[2], a3 = sp[3];
            float o = a0.x * v[0] + a0.y * v[1] + a0.z * v[2] + a0.w * v[3]
                    + a1.x * v[4] + a1.y * v[5] + a1.z * v[6] + a1.w * v[7]
                    + a2.x * v[8] + a2.y * v[9] + a2.z * v[10] + a2.w * v[11]
                    + a3.x * v[12] + a3.y * v[13] + a3.z * v[14] + a3.w * v[15];
            const int n = (ghi * 4 + (q >> 2)) * 64 + gwi * 4 + (q & 3);
            const float xr = x[(nb + n) * 256 + h * 64 + d];
            qk[q][h * 64 + d] = o + xr;
        }
    }
    __syncthreads();

    {
        const int wv = tid >> 6, lane = tid & 63;
        const float4 gw = ((const float4*)gnw)[lane];
        const float4 gb = ((const float4*)gnb)[lane];
        #pragma unroll
        for (int i = 0; i < 4; ++i) {
            const int t = wv * 4 + i;
            const float4 zv = *(const float4*)&qk[t][lane * 4];
            float ssum = zv.x + zv.y + zv.z + zv.w;
            for (int off = 1; off < 64; off <<= 1) ssum += __shfl_xor(ssum, off);
            const float u = ssum * (1.f / 256.f);
            const float dx = zv.x - u, dy = zv.y - u, dz = zv.z - u, dw = zv.w - u;
            float vsum = dx * dx + dy * dy + dz * dz + dw * dw;
            for (int off = 1; off < 64; off <<= 1) vsum += __shfl_xor(vsum, off);
            const float rinv = rsqrtf(vsum * (1.f / 256.f) + LN_EPS);
            float4 y;
            y.x = gw.x * dx * rinv + gb.x;
            y.y = gw.y * dy * rinv + gb.y;
            y.z = gw.z * dz * rinv + gb.z;
            y.w = gw.w * dw * rinv + gb.w;
            *(float4*)&qk[t][lane * 4] = y;
            const int n = (ghi * 4 + (t >> 2)) * 64 + gwi * 4 + (t & 3);
            short4 sv;
            sv.x = (short)f2bf(y.x); sv.y = (short)f2bf(y.y);
            sv.z = (short)f2bf(y.z); sv.w = (short)f2bf(y.w);
            *(short4*)(lnb + (nb + n) * 256 + lane * 4) = sv;
        }
    }
    __syncthreads();

    {
        float ps = 0.f;
        #pragma unroll
        for (int t = 0; t < 16; ++t) ps += qk[t][tid];
        pooledb[((size_t)b * 256 + win) * 256 + tid] = (short)f2bf(ps * (1.f / 16.f));
    }
}

// ---------------------------------------------------------------------------
// Pooled global attention via MFMA. Block = (b, h, 128-q-row tile), grid 2048,
// 4 waves x 32 q-rows. K in LDS [256][64] swz, V^T in LDS [64][256] swz,
// unnormalized bf16 P per wave in LDS (Cp=280), deferred normalization.
// Output gx = attn + ln residual, f32.
// ---------------------------------------------------------------------------
#define CP 280
__global__ __launch_bounds__(256, 1) void k_glb(
    const short* __restrict__ qgb, const short* __restrict__ kb,
    const short* __restrict__ vtb, const short* __restrict__ lnb,
    float* __restrict__ gxf)
{
    __shared__ short Ks[256 * 64];
    __shared__ short Vt[64 * 256];
    __shared__ short Pl[4][32 * CP];

    const int tid = threadIdx.x;
    const int bid = (blockIdx.x & 7) * 256 + (blockIdx.x >> 3);
    const int bh = bid >> 5, qt = bid & 31;
    const int b = bh >> 2, h = bh & 3;
    const int q0 = qt * 128;
    const size_t nb = (size_t)b * 4096;

    // stage K [256 keys][64 d], swizzled
    #pragma unroll
    for (int i = 0; i < 8; ++i) {
        const int c = i * 256 + tid;
        const int p = c >> 3, d8 = (c & 7) * 8;
        const uint4 u = *(const uint4*)(kb + ((size_t)(b * 256 + p)) * 256 + h * 64 + d8);
        *(uint4*)&Ks[p * 64 + (d8 ^ ((p & 7) << 3))] = u;
    }
    // stage V^T [64 d][256 keys], swizzled
    const short* vsrc = vtb + (size_t)bh * 16384;
    #pragma unroll
    for (int i = 0; i < 8; ++i) {
        const int c = i * 256 + tid;
        const int d = c >> 5, k8 = (c & 31) * 8;
        const uint4 u = *(const uint4*)(vsrc + d * 256 + k8);
        *(uint4*)&Vt[d * 256 + (k8 ^ ((d & 7) << 3))] = u;
    }
    __syncthreads();

    const int w = tid >> 6, lane = tid & 63;
    const int g = lane >> 4, l15 = lane & 15;

    // Q A-fragments straight from global
    bf16x8 aq[2][2];
    #pragma unroll
    for (int mt = 0; mt < 2; ++mt) {
        const int n = q0 + w * 32 + mt * 16 + l15;
        const short* qp = qgb + (nb + n) * 256 + h * 64 + g * 8;
        aq[mt][0] = *(const bf16x8*)qp;
        aq[mt][1] = *(const bf16x8*)(qp + 32);
    }

    // S = Q K^T : acc[mt][nt] covers q rows mt*16+(4g+e), keys nt*16+l15
    f32x4 acc[2][16];
    #pragma unroll
    for (int mt = 0; mt < 2; ++mt)
        #pragma unroll
        for (int nt = 0; nt < 16; ++nt) acc[mt][nt] = (f32x4)0.f;

    #pragma unroll
    for (int nt = 0; nt < 16; ++nt) {
        const int key = nt * 16 + l15;
        const int sw = (key & 7) << 3;
        const bf16x8 bk0 = *(const bf16x8*)&Ks[key * 64 + ((g * 8) ^ sw)];
        const bf16x8 bk1 = *(const bf16x8*)&Ks[key * 64 + ((g * 8 + 32) ^ sw)];
        acc[0][nt] = __builtin_amdgcn_mfma_f32_16x16x32_bf16(aq[0][0], bk0, acc[0][nt], 0, 0, 0);
        acc[1][nt] = __builtin_amdgcn_mfma_f32_16x16x32_bf16(aq[1][0], bk0, acc[1][nt], 0, 0, 0);
        acc[0][nt] = __builtin_amdgcn_mfma_f32_16x16x32_bf16(aq[0][1], bk1, acc[0][nt], 0, 0, 0);
        acc[1][nt] = __builtin_amdgcn_mfma_f32_16x16x32_bf16(aq[1][1], bk1, acc[1][nt], 0, 0, 0);
    }

    // exp (no max-sub; scores small), row-sum partials, unnormalized P -> LDS
    float rs[2][4];
    short* Pw = &Pl[w][0];
    #pragma unroll
    for (int mt = 0; mt < 2; ++mt) {
        #pragma unroll
        for (int e = 0; e < 4; ++e) {
            const int prow = (mt * 16 + g * 4 + e) * CP;
            float rsum = 0.f;
            #pragma unroll
            for (int nt = 0; nt < 16; ++nt) {
                const float p = __expf(acc[mt][nt][e] * SCALE);
                rsum += p;
                Pw[prow + nt * 16 + l15] = (short)f2bf(p);
            }
            rs[mt][e] = rsum;
        }
    }
    // reduce row-sums across the 16 lanes holding the row's keys
    #pragma unroll
    for (int mt = 0; mt < 2; ++mt)
        #pragma unroll
        for (int e = 0; e < 4; ++e) {
            float v = rs[mt][e];
            v += __shfl_xor(v, 1); v += __shfl_xor(v, 2);
            v += __shfl_xor(v, 4); v += __shfl_xor(v, 8);
            rs[mt][e] = v;
        }

    // O = P V (unnormalized), keys as K-dim in 8 steps of 32
    f32x4 oc[2][4];
    #pragma unroll
    for (int mt = 0; mt < 2; ++mt)
        #pragma unroll
        for (int nt = 0; nt < 4; ++nt) oc[mt][nt] = (f32x4)0.f;

    #pragma unroll
    for (int ks = 0; ks < 8; ++ks) {
        const int kc = ks * 32 + g * 8;
        const bf16x8 a0 = *(const bf16x8*)&Pw[l15 * CP + kc];
        const bf16x8 a1 = *(const bf16x8*)&Pw[(16 + l15) * CP + kc];
        #pragma unroll
        for (int nt = 0; nt < 4; ++nt) {
            const int d = nt * 16 + l15;
            const bf16x8 bv = *(const bf16x8*)&Vt[d * 256 + (kc ^ ((d & 7) << 3))];
            oc[0][nt] = __builtin_amdgcn_mfma_f32_16x16x32_bf16(a0, bv, oc[0][nt], 0, 0, 0);
            oc[1][nt] = __builtin_amdgcn_mfma_f32_16x16x32_bf16(a1, bv, oc[1][nt], 0, 0, 0);
        }
    }

    // epilogue: normalize, residual, f32 store
    #pragma unroll
    for (int mt = 0; mt < 2; ++mt) {
        #pragma unroll
        for (int e = 0; e < 4; ++e) {
            const float inv = 1.f / rs[mt][e];
            const int n = q0 + w * 32 + mt * 16 + g * 4 + e;
            const size_t base = (nb + n) * 256 + h * 64;
            #pragma unroll
            for (int nt = 0; nt < 4; ++nt) {
                const int d = nt * 16 + l15;
                gxf[base + d] = oc[mt][nt][e] * inv + bf2f(lnb[base + d]);
            }
        }
    }
}

// ---------------------------------------------------------------------------
extern "C" void kernel_launch(void* const* d_in, const int* in_sizes, int n_in,
                              void* d_out, int out_size, void* d_ws, size_t ws_size,
                              hipStream_t stream)
{
    (void)in_sizes; (void)n_in; (void)out_size; (void)ws_size;
    const float* x     = (const float*)d_in[0];
    const float* wqkv  = (const float*)d_in[1];
    const float* bqkv  = (const float*)d_in[2];
    const float* wq    = (const float*)d_in[3];
    const float* bq    = (const float*)d_in[4];
    const float* wkv   = (const float*)d_in[5];
    const float* bkv   = (const float*)d_in[6];
    const float* wproj = (const float*)d_in[7];
    const float* bproj = (const float*)d_in[8];
    const float* gnw   = (const float*)d_in[9];
    const float* gnb   = (const float*)d_in[10];
    float* out = (float*)d_out;

    char* wsb = (char*)d_ws;
    short* wb      = (short*)(wsb + 0);            // cast weights (bf16)
    short* qkvb    = (short*)(wsb + 1048576);      // 65536 x 768
    short* lnb     = (short*)(wsb + 101711872);    // 65536 x 256
    short* qgb     = (short*)(wsb + 135266304);    // 65536 x 256
    short* kb      = (short*)(wsb + 168820736);    // 4096 x 256 (K)
    short* vtb     = (short*)(wsb + 170917888);    // 64bh x 64d x 256p (V^T)
    short* pooledb = (short*)(wsb + 173015040);    // 4096 x 256
    float* gxf     = (float*)(wsb + 175112192);    // 65536 x 256 f32

    k_castw<<<dim3(224), dim3(256), 0, stream>>>(wqkv, wq, wkv, wproj, wb);
    // qkv = x @ Wqkv^T + b            (65536 x 768, K=256)
    k_gemm<1, 1><<<dim3(3072), dim3(256), 0, stream>>>(x, wb, bqkv, qkvb, nullptr, 768, 6);
    // window attention + LN + pool
    k_win2<<<dim3(4096), dim3(256), 0, stream>>>(qkvb, x, gnw, gnb, lnb, pooledb);
    // qg = ln @ Wq^T + b              (65536 x 256)
    k_gemm<0, 1><<<dim3(1024), dim3(256), 0, stream>>>(lnb, wb + 196608, bq, qgb, nullptr, 256, 2);
    // kv = pooled @ Wkv^T + b, split K / V^T
    k_gemm<0, 2><<<dim3(128), dim3(256), 0, stream>>>(pooledb, wb + 262144, bkv, kb, vtb, 512, 4);
    // pooled global attention + residual (MFMA)
    k_glb<<<dim3(2048), dim3(256), 0, stream>>>(qgb, kb, vtb, lnb, gxf);
    // out = gx @ Wproj^T + b          (65536 x 256, f32 in/out)
    k_gemm<1, 0><<<dim3(1024), dim3(256), 0, stream>>>(gxf, wb + 393216, bproj, out, nullptr, 256, 2);
}

// Round 4
// 237.189 us; speedup vs baseline: 7.9012x; 1.1091x over previous
//
#include <hip/hip_runtime.h>
#include <cstddef>

#define SCALE 0.125f
#define LN_EPS 1e-6f

typedef __attribute__((ext_vector_type(8))) short bf16x8;
typedef __attribute__((ext_vector_type(4))) float f32x4;

__device__ __forceinline__ unsigned short f2bf(float f) {
    unsigned u = __float_as_uint(f);
    return (unsigned short)((u + 0x7FFFu + ((u >> 16) & 1u)) >> 16);
}
__device__ __forceinline__ unsigned pack2(float a, float b) {
    return (unsigned)f2bf(a) | ((unsigned)f2bf(b) << 16);
}
__device__ __forceinline__ float bflo(unsigned v) { return __uint_as_float(v << 16); }
__device__ __forceinline__ float bfhi(unsigned v) { return __uint_as_float(v & 0xFFFF0000u); }
__device__ __forceinline__ float bf2f(short s) { return __uint_as_float(((unsigned)(unsigned short)s) << 16); }

#define GLOAD16(gp, lp) __builtin_amdgcn_global_load_lds( \
    (const __attribute__((address_space(1))) void*)(gp),  \
    (__attribute__((address_space(3))) void*)(lp), 16, 0, 0)

// ---------------------------------------------------------------------------
// Cast all 4 weight matrices f32 -> bf16 into wb.
// ---------------------------------------------------------------------------
__global__ __launch_bounds__(256) void k_castw(
    const float* __restrict__ wqkv, const float* __restrict__ wq,
    const float* __restrict__ wkv, const float* __restrict__ wproj,
    short* __restrict__ wb)
{
    const int blk = blockIdx.x;
    const float* src; size_t so, doff;
    if (blk < 96)       { src = wqkv;  so = (size_t)blk * 2048;         doff = 0; }
    else if (blk < 128) { src = wq;    so = (size_t)(blk - 96) * 2048;  doff = 196608; }
    else if (blk < 192) { src = wkv;   so = (size_t)(blk - 128) * 2048; doff = 262144; }
    else                { src = wproj; so = (size_t)(blk - 192) * 2048; doff = 393216; }
    const size_t idx = so + (size_t)threadIdx.x * 8;
    const float4 f0 = *(const float4*)(src + idx);
    const float4 f1 = *(const float4*)(src + idx + 4);
    uint4 o;
    o.x = pack2(f0.x, f0.y); o.y = pack2(f0.z, f0.w);
    o.z = pack2(f1.x, f1.y); o.w = pack2(f1.z, f1.w);
    *(uint4*)(wb + doff + idx) = o;
}

// ---------------------------------------------------------------------------
// Cast x (16.78M f32) -> bf16. 8192 blocks x 2048 elems.
// ---------------------------------------------------------------------------
__global__ __launch_bounds__(256) void k_castx(
    const float* __restrict__ x, short* __restrict__ xb)
{
    const size_t i = ((size_t)blockIdx.x * 256 + threadIdx.x) * 8;
    const float4 f0 = *(const float4*)(x + i);
    const float4 f1 = *(const float4*)(x + i + 4);
    uint4 o;
    o.x = pack2(f0.x, f0.y); o.y = pack2(f0.z, f0.w);
    o.z = pack2(f1.x, f1.y); o.w = pack2(f1.z, f1.w);
    *(uint4*)(xb + i) = o;
}

// ---------------------------------------------------------------------------
// MFMA GEMM: C[M][ldc] = A[M][256] @ Bw[N][256]^T + bias. A, Bw bf16.
// Tile 128x128, BK=64, 4 K-tiles, double-buffered LDS staged via
// global_load_lds (linear dest, XOR-swizzled SOURCE granule; reads re-apply
// the XOR). 4 waves x 64x64 (acc[4][4]).
// OUTMODE: 0 = f32 linear, 1 = bf16 linear, 2 = kv-split:
//   cols 0..255  -> Cdst[row*256+col] bf16           (K, row-major)
//   cols 256..511-> Vdst[((b*4+h)*64+d)*256+p] bf16  (V transposed per (b,h))
// ---------------------------------------------------------------------------
template<int OUTMODE>
__global__ __launch_bounds__(256, 2) void k_gemm(
    const short* __restrict__ Asrc, const short* __restrict__ Bw,
    const float* __restrict__ bias, void* __restrict__ Cdst,
    short* __restrict__ Vdst, int ldc, int nbn)
{
    __shared__ short As[2][128 * 64];
    __shared__ short Bs[2][128 * 64];

    const int tid = threadIdx.x;
    const int q8 = gridDim.x >> 3;
    const int bid = (blockIdx.x & 7) * q8 + (blockIdx.x >> 3);
    const int bm = bid / nbn, bn = bid % nbn;
    const size_t m0 = (size_t)bm * 128, n0 = (size_t)bn * 128;
    const int wid = tid >> 6, lane = tid & 63;
    const int wr = wid >> 1, wc = wid & 1;
    const int g = lane >> 4, r = lane & 15;
    const int rowc = lane >> 3, gran = lane & 7;   // staging: 8 rows x 8 granules

    f32x4 acc[4][4];
    #pragma unroll
    for (int mi = 0; mi < 4; ++mi)
        #pragma unroll
        for (int nj = 0; nj < 4; ++nj) acc[mi][nj] = (f32x4)0.f;

    // wave 'wid' stages rows [wid*32, wid*32+32) of both A and B tiles.
    auto STAGE = [&](int kt, int bufi) {
        const int k0 = kt * 64;
        #pragma unroll
        for (int i = 0; i < 4; ++i) {
            const int rbase = wid * 32 + i * 8;
            const int row = rbase + rowc;
            const int sg = gran ^ (row & 7);       // pre-swizzled source granule
            GLOAD16(Asrc + (m0 + row) * 256 + k0 + sg * 8, &As[bufi][rbase * 64]);
            GLOAD16(Bw   + (n0 + row) * 256 + k0 + sg * 8, &Bs[bufi][rbase * 64]);
        }
    };

    auto COMPUTE = [&](int bufi) {
        #pragma unroll
        for (int ks = 0; ks < 2; ++ks) {
            const int ke = ks * 32 + g * 8;
            bf16x8 a[4], b[4];
            #pragma unroll
            for (int mi = 0; mi < 4; ++mi) {
                const int row = wr * 64 + mi * 16 + r;
                a[mi] = *(const bf16x8*)&As[bufi][row * 64 + (ke ^ ((row & 7) << 3))];
            }
            #pragma unroll
            for (int nj = 0; nj < 4; ++nj) {
                const int row = wc * 64 + nj * 16 + r;
                b[nj] = *(const bf16x8*)&Bs[bufi][row * 64 + (ke ^ ((row & 7) << 3))];
            }
            #pragma unroll
            for (int mi = 0; mi < 4; ++mi)
                #pragma unroll
                for (int nj = 0; nj < 4; ++nj)
                    acc[mi][nj] = __builtin_amdgcn_mfma_f32_16x16x32_bf16(
                        a[mi], b[nj], acc[mi][nj], 0, 0, 0);
        }
    };

    STAGE(0, 0);
    __syncthreads();
    #pragma unroll
    for (int kt = 0; kt < 4; ++kt) {
        const int cur = kt & 1;
        if (kt < 3) STAGE(kt + 1, cur ^ 1);   // prefetch next tile (in flight)
        COMPUTE(cur);
        __syncthreads();                       // drains vmcnt + lgkmcnt
    }

    #pragma unroll
    for (int nj = 0; nj < 4; ++nj) {
        const size_t col = n0 + wc * 64 + nj * 16 + r;
        const float bv = bias[col];
        #pragma unroll
        for (int mi = 0; mi < 4; ++mi) {
            const size_t row = m0 + wr * 64 + mi * 16 + g * 4;
            #pragma unroll
            for (int e = 0; e < 4; ++e) {
                const float v = acc[mi][nj][e] + bv;
                const size_t rr = row + e;
                if (OUTMODE == 0) ((float*)Cdst)[rr * ldc + col] = v;
                else if (OUTMODE == 1) ((short*)Cdst)[rr * ldc + col] = (short)f2bf(v);
                else {
                    const int colk = (int)col - 256;
                    if (colk < 0) ((short*)Cdst)[rr * 256 + col] = (short)f2bf(v);
                    else {
                        const int hh = colk >> 6, dd = colk & 63;
                        Vdst[((((rr >> 8) * 4 + hh) * 64 + dd) << 8) + (rr & 255)] = (short)f2bf(v);
                    }
                }
            }
        }
    }
}

// ---------------------------------------------------------------------------
// Window attention + residual + LN + pool (unchanged).
// ---------------------------------------------------------------------------
__global__ __launch_bounds__(256) void k_win2(
    const short* __restrict__ qkvb, const float* __restrict__ x,
    const float* __restrict__ gnw, const float* __restrict__ gnb,
    short* __restrict__ lnb, short* __restrict__ pooledb)
{
    __shared__ float qk[16][772];
    __shared__ float sm[4][16][16];

    const int tid = threadIdx.x;
    const int blk = blockIdx.x;
    const int b = blk >> 8, win = blk & 255;
    const int ghi = win >> 4, gwi = win & 15;
    const size_t nb = (size_t)b * 4096;

    {
        const int t = tid >> 4, l16 = tid & 15;
        const int n = (ghi * 4 + (t >> 2)) * 64 + gwi * 4 + (t & 3);
        const short* gp = qkvb + (nb + n) * 768;
        #pragma unroll
        for (int j = 0; j < 6; ++j) {
            const int c16 = l16 + j * 16;
            const uint4 u = *(const uint4*)(gp + c16 * 8);
            float4 a, c;
            a.x = bflo(u.x); a.y = bfhi(u.x); a.z = bflo(u.y); a.w = bfhi(u.y);
            c.x = bflo(u.z); c.y = bfhi(u.z); c.z = bflo(u.w); c.w = bfhi(u.w);
            *(float4*)&qk[t][c16 * 8] = a;
            *(float4*)&qk[t][c16 * 8 + 4] = c;
        }
    }
    __syncthreads();

    {
        const int h = tid >> 6, q = (tid >> 2) & 15, r = tid & 3;
        float4 qv[16];
        const float4* qrow = (const float4*)&qk[q][h * 64];
        #pragma unroll
        for (int i = 0; i < 16; ++i) qv[i] = qrow[i];
        #pragma unroll
        for (int i = 0; i < 4; ++i) {
            const int kt = i * 4 + r;
            const float4* krow = (const float4*)&qk[kt][256 + h * 64];
            float acc = 0.f;
            #pragma unroll
            for (int c4 = 0; c4 < 16; ++c4) {
                const float4 kk = krow[c4];
                acc += qv[c4].x * kk.x + qv[c4].y * kk.y + qv[c4].z * kk.z + qv[c4].w * kk.w;
            }
            sm[h][q][kt] = acc * SCALE;
        }
    }
    __syncthreads();

    if (tid < 64) {
        const int h = tid >> 4, q = tid & 15;
        float4* sp = (float4*)&sm[h][q][0];
        float4 s0 = sp[0], s1 = sp[1], s2 = sp[2], s3 = sp[3];
        float m = fmaxf(fmaxf(fmaxf(fmaxf(s0.x, s0.y), fmaxf(s0.z, s0.w)),
                              fmaxf(fmaxf(s1.x, s1.y), fmaxf(s1.z, s1.w))),
                        fmaxf(fmaxf(fmaxf(s2.x, s2.y), fmaxf(s2.z, s2.w)),
                              fmaxf(fmaxf(s3.x, s3.y), fmaxf(s3.z, s3.w))));
        s0.x = __expf(s0.x - m); s0.y = __expf(s0.y - m); s0.z = __expf(s0.z - m); s0.w = __expf(s0.w - m);
        s1.x = __expf(s1.x - m); s1.y = __expf(s1.y - m); s1.z = __expf(s1.z - m); s1.w = __expf(s1.w - m);
        s2.x = __expf(s2.x - m); s2.y = __expf(s2.y - m); s2.z = __expf(s2.z - m); s2.w = __expf(s2.w - m);
        s3.x = __expf(s3.x - m); s3.y = __expf(s3.y - m); s3.z = __expf(s3.z - m); s3.w = __expf(s3.w - m);
        const float l = s0.x + s0.y + s0.z + s0.w + s1.x + s1.y + s1.z + s1.w
                      + s2.x + s2.y + s2.z + s2.w + s3.x + s3.y + s3.z + s3.w;
        const float inv = 1.f / l;
        s0.x *= inv; s0.y *= inv; s0.z *= inv; s0.w *= inv;
        s1.x *= inv; s1.y *= inv; s1.z *= inv; s1.w *= inv;
        s2.x *= inv; s2.y *= inv; s2.z *= inv; s2.w *= inv;
        s3.x *= inv; s3.y *= inv; s3.z *= inv; s3.w *= inv;
        sp[0] = s0; sp[1] = s1; sp[2] = s2; sp[3] = s3;
    }
    __syncthreads();

    {
        const int h = tid >> 6, d = tid & 63;
        float v[16];
        #pragma unroll
        for (int kt = 0; kt < 16; ++kt) v[kt] = qk[kt][512 + h * 64 + d];
        #pragma unroll
        for (int q = 0; q < 16; ++q) {
            const float4* sp = (const float4*)&sm[h][q][0];
            const float4 a0 = sp[0], a1 = sp[1], a2 = sp[2], a3 = sp[3];
            float o = a0.x * v[0] + a0.y * v[1] + a0.z * v[2] + a0.w * v[3]
                    + a1.x * v[4] + a1.y * v[5] + a1.z * v[6] + a1.w * v[7]
                    + a2.x * v[8] + a2.y * v[9] + a2.z * v[10] + a2.w * v[11]
                    + a3.x * v[12] + a3.y * v[13] + a3.z * v[14] + a3.w * v[15];
            const int n = (ghi * 4 + (q >> 2)) * 64 + gwi * 4 + (q & 3);
            const float xr = x[(nb + n) * 256 + h * 64 + d];
            qk[q][h * 64 + d] = o + xr;
        }
    }
    __syncthreads();

    {
        const int wv = tid >> 6, lane = tid & 63;
        const float4 gw = ((const float4*)gnw)[lane];
        const float4 gb = ((const float4*)gnb)[lane];
        #pragma unroll
        for (int i = 0; i < 4; ++i) {
            const int t = wv * 4 + i;
            const float4 zv = *(const float4*)&qk[t][lane * 4];
            float ssum = zv.x + zv.y + zv.z + zv.w;
            for (int off = 1; off < 64; off <<= 1) ssum += __shfl_xor(ssum, off);
            const float u = ssum * (1.f / 256.f);
            const float dx = zv.x - u, dy = zv.y - u, dz = zv.z - u, dw = zv.w - u;
            float vsum = dx * dx + dy * dy + dz * dz + dw * dw;
            for (int off = 1; off < 64; off <<= 1) vsum += __shfl_xor(vsum, off);
            const float rinv = rsqrtf(vsum * (1.f / 256.f) + LN_EPS);
            float4 y;
            y.x = gw.x * dx * rinv + gb.x;
            y.y = gw.y * dy * rinv + gb.y;
            y.z = gw.z * dz * rinv + gb.z;
            y.w = gw.w * dw * rinv + gb.w;
            *(float4*)&qk[t][lane * 4] = y;
            const int n = (ghi * 4 + (t >> 2)) * 64 + gwi * 4 + (t & 3);
            short4 sv;
            sv.x = (short)f2bf(y.x); sv.y = (short)f2bf(y.y);
            sv.z = (short)f2bf(y.z); sv.w = (short)f2bf(y.w);
            *(short4*)(lnb + (nb + n) * 256 + lane * 4) = sv;
        }
    }
    __syncthreads();

    {
        float ps = 0.f;
        #pragma unroll
        for (int t = 0; t < 16; ++t) ps += qk[t][tid];
        pooledb[((size_t)b * 256 + win) * 256 + tid] = (short)f2bf(ps * (1.f / 16.f));
    }
}

// ---------------------------------------------------------------------------
// Pooled global attention via MFMA (structure unchanged; bf16 output).
// ---------------------------------------------------------------------------
#define CP 280
__global__ __launch_bounds__(256, 1) void k_glb(
    const short* __restrict__ qgb, const short* __restrict__ kb,
    const short* __restrict__ vtb, const short* __restrict__ lnb,
    short* __restrict__ gxb)
{
    __shared__ short Ks[256 * 64];
    __shared__ short Vt[64 * 256];
    __shared__ short Pl[4][32 * CP];

    const int tid = threadIdx.x;
    const int bid = (blockIdx.x & 7) * 256 + (blockIdx.x >> 3);
    const int bh = bid >> 5, qt = bid & 31;
    const int b = bh >> 2, h = bh & 3;
    const int q0 = qt * 128;
    const size_t nb = (size_t)b * 4096;

    #pragma unroll
    for (int i = 0; i < 8; ++i) {
        const int c = i * 256 + tid;
        const int p = c >> 3, d8 = (c & 7) * 8;
        const uint4 u = *(const uint4*)(kb + ((size_t)(b * 256 + p)) * 256 + h * 64 + d8);
        *(uint4*)&Ks[p * 64 + (d8 ^ ((p & 7) << 3))] = u;
    }
    const short* vsrc = vtb + (size_t)bh * 16384;
    #pragma unroll
    for (int i = 0; i < 8; ++i) {
        const int c = i * 256 + tid;
        const int d = c >> 5, k8 = (c & 31) * 8;
        const uint4 u = *(const uint4*)(vsrc + d * 256 + k8);
        *(uint4*)&Vt[d * 256 + (k8 ^ ((d & 7) << 3))] = u;
    }
    __syncthreads();

    const int w = tid >> 6, lane = tid & 63;
    const int g = lane >> 4, l15 = lane & 15;

    bf16x8 aq[2][2];
    #pragma unroll
    for (int mt = 0; mt < 2; ++mt) {
        const int n = q0 + w * 32 + mt * 16 + l15;
        const short* qp = qgb + (nb + n) * 256 + h * 64 + g * 8;
        aq[mt][0] = *(const bf16x8*)qp;
        aq[mt][1] = *(const bf16x8*)(qp + 32);
    }

    f32x4 acc[2][16];
    #pragma unroll
    for (int mt = 0; mt < 2; ++mt)
        #pragma unroll
        for (int nt = 0; nt < 16; ++nt) acc[mt][nt] = (f32x4)0.f;

    #pragma unroll
    for (int nt = 0; nt < 16; ++nt) {
        const int key = nt * 16 + l15;
        const int sw = (key & 7) << 3;
        const bf16x8 bk0 = *(const bf16x8*)&Ks[key * 64 + ((g * 8) ^ sw)];
        const bf16x8 bk1 = *(const bf16x8*)&Ks[key * 64 + ((g * 8 + 32) ^ sw)];
        acc[0][nt] = __builtin_amdgcn_mfma_f32_16x16x32_bf16(aq[0][0], bk0, acc[0][nt], 0, 0, 0);
        acc[1][nt] = __builtin_amdgcn_mfma_f32_16x16x32_bf16(aq[1][0], bk0, acc[1][nt], 0, 0, 0);
        acc[0][nt] = __builtin_amdgcn_mfma_f32_16x16x32_bf16(aq[0][1], bk1, acc[0][nt], 0, 0, 0);
        acc[1][nt] = __builtin_amdgcn_mfma_f32_16x16x32_bf16(aq[1][1], bk1, acc[1][nt], 0, 0, 0);
    }

    float rs[2][4];
    short* Pw = &Pl[w][0];
    #pragma unroll
    for (int mt = 0; mt < 2; ++mt) {
        #pragma unroll
        for (int e = 0; e < 4; ++e) {
            const int prow = (mt * 16 + g * 4 + e) * CP;
            float rsum = 0.f;
            #pragma unroll
            for (int nt = 0; nt < 16; ++nt) {
                const float p = __expf(acc[mt][nt][e] * SCALE);
                rsum += p;
                Pw[prow + nt * 16 + l15] = (short)f2bf(p);
            }
            rs[mt][e] = rsum;
        }
    }
    #pragma unroll
    for (int mt = 0; mt < 2; ++mt)
        #pragma unroll
        for (int e = 0; e < 4; ++e) {
            float v = rs[mt][e];
            v += __shfl_xor(v, 1); v += __shfl_xor(v, 2);
            v += __shfl_xor(v, 4); v += __shfl_xor(v, 8);
            rs[mt][e] = v;
        }

    f32x4 oc[2][4];
    #pragma unroll
    for (int mt = 0; mt < 2; ++mt)
        #pragma unroll
        for (int nt = 0; nt < 4; ++nt) oc[mt][nt] = (f32x4)0.f;

    #pragma unroll
    for (int ks = 0; ks < 8; ++ks) {
        const int kc = ks * 32 + g * 8;
        const bf16x8 a0 = *(const bf16x8*)&Pw[l15 * CP + kc];
        const bf16x8 a1 = *(const bf16x8*)&Pw[(16 + l15) * CP + kc];
        #pragma unroll
        for (int nt = 0; nt < 4; ++nt) {
            const int d = nt * 16 + l15;
            const bf16x8 bv = *(const bf16x8*)&Vt[d * 256 + (kc ^ ((d & 7) << 3))];
            oc[0][nt] = __builtin_amdgcn_mfma_f32_16x16x32_bf16(a0, bv, oc[0][nt], 0, 0, 0);
            oc[1][nt] = __builtin_amdgcn_mfma_f32_16x16x32_bf16(a1, bv, oc[1][nt], 0, 0, 0);
        }
    }

    #pragma unroll
    for (int mt = 0; mt < 2; ++mt) {
        #pragma unroll
        for (int e = 0; e < 4; ++e) {
            const float inv = 1.f / rs[mt][e];
            const int n = q0 + w * 32 + mt * 16 + g * 4 + e;
            const size_t base = (nb + n) * 256 + h * 64;
            #pragma unroll
            for (int nt = 0; nt < 4; ++nt) {
                const int d = nt * 16 + l15;
                gxb[base + d] = (short)f2bf(oc[mt][nt][e] * inv + bf2f(lnb[base + d]));
            }
        }
    }
}

// ---------------------------------------------------------------------------
extern "C" void kernel_launch(void* const* d_in, const int* in_sizes, int n_in,
                              void* d_out, int out_size, void* d_ws, size_t ws_size,
                              hipStream_t stream)
{
    (void)in_sizes; (void)n_in; (void)out_size; (void)ws_size;
    const float* x     = (const float*)d_in[0];
    const float* wqkv  = (const float*)d_in[1];
    const float* bqkv  = (const float*)d_in[2];
    const float* wq    = (const float*)d_in[3];
    const float* bq    = (const float*)d_in[4];
    const float* wkv   = (const float*)d_in[5];
    const float* bkv   = (const float*)d_in[6];
    const float* wproj = (const float*)d_in[7];
    const float* bproj = (const float*)d_in[8];
    const float* gnw   = (const float*)d_in[9];
    const float* gnb   = (const float*)d_in[10];
    float* out = (float*)d_out;

    char* wsb = (char*)d_ws;
    short* wb      = (short*)(wsb + 0);            // cast weights (bf16)
    short* qkvb    = (short*)(wsb + 1048576);      // 65536 x 768
    short* lnb     = (short*)(wsb + 101711872);    // 65536 x 256
    short* qgb     = (short*)(wsb + 135266304);    // 65536 x 256
    short* kb      = (short*)(wsb + 168820736);    // 4096 x 256 (K)
    short* vtb     = (short*)(wsb + 170917888);    // 64bh x 64d x 256p (V^T)
    short* pooledb = (short*)(wsb + 173015040);    // 4096 x 256
    short* gxb     = (short*)(wsb + 175112192);    // 65536 x 256 bf16
    short* xb      = (short*)(wsb + 208666624);    // 65536 x 256 bf16 (x cast)

    k_castw<<<dim3(224),  dim3(256), 0, stream>>>(wqkv, wq, wkv, wproj, wb);
    k_castx<<<dim3(8192), dim3(256), 0, stream>>>(x, xb);
    // qkv = x @ Wqkv^T + b            (65536 x 768, K=256)
    k_gemm<1><<<dim3(3072), dim3(256), 0, stream>>>(xb, wb, bqkv, qkvb, nullptr, 768, 6);
    // window attention + LN + pool
    k_win2<<<dim3(4096), dim3(256), 0, stream>>>(qkvb, x, gnw, gnb, lnb, pooledb);
    // qg = ln @ Wq^T + b              (65536 x 256)
    k_gemm<1><<<dim3(1024), dim3(256), 0, stream>>>(lnb, wb + 196608, bq, qgb, nullptr, 256, 2);
    // kv = pooled @ Wkv^T + b, split K / V^T
    k_gemm<2><<<dim3(128), dim3(256), 0, stream>>>(pooledb, wb + 262144, bkv, kb, vtb, 512, 4);
    // pooled global attention + residual (MFMA)
    k_glb<<<dim3(2048), dim3(256), 0, stream>>>(qgb, kb, vtb, lnb, gxb);
    // out = gx @ Wproj^T + b          (65536 x 256, f32 out)
    k_gemm<0><<<dim3(1024), dim3(256), 0, stream>>>(gxb, wb + 393216, bproj, out, nullptr, 256, 2);
}

// Round 5
// 226.288 us; speedup vs baseline: 8.2818x; 1.0482x over previous
//
#include <hip/hip_runtime.h>
#include <cstddef>

#define SCALE 0.125f
#define LN_EPS 1e-6f

typedef __attribute__((ext_vector_type(8))) short bf16x8;
typedef __attribute__((ext_vector_type(4))) float f32x4;

__device__ __forceinline__ unsigned short f2bf(float f) {
    unsigned u = __float_as_uint(f);
    return (unsigned short)((u + 0x7FFFu + ((u >> 16) & 1u)) >> 16);
}
__device__ __forceinline__ unsigned pack2(float a, float b) {
    return (unsigned)f2bf(a) | ((unsigned)f2bf(b) << 16);
}
__device__ __forceinline__ float bflo(unsigned v) { return __uint_as_float(v << 16); }
__device__ __forceinline__ float bfhi(unsigned v) { return __uint_as_float(v & 0xFFFF0000u); }
__device__ __forceinline__ float bf2f(short s) { return __uint_as_float(((unsigned)(unsigned short)s) << 16); }

#define GLOAD16(gp, lp) __builtin_amdgcn_global_load_lds( \
    (const __attribute__((address_space(1))) void*)(gp),  \
    (__attribute__((address_space(3))) void*)(lp), 16, 0, 0)

// ---------------------------------------------------------------------------
// Cast all 4 weight matrices f32 -> bf16 into wb.
// ---------------------------------------------------------------------------
__global__ __launch_bounds__(256) void k_castw(
    const float* __restrict__ wqkv, const float* __restrict__ wq,
    const float* __restrict__ wkv, const float* __restrict__ wproj,
    short* __restrict__ wb)
{
    const int blk = blockIdx.x;
    const float* src; size_t so, doff;
    if (blk < 96)       { src = wqkv;  so = (size_t)blk * 2048;         doff = 0; }
    else if (blk < 128) { src = wq;    so = (size_t)(blk - 96) * 2048;  doff = 196608; }
    else if (blk < 192) { src = wkv;   so = (size_t)(blk - 128) * 2048; doff = 262144; }
    else                { src = wproj; so = (size_t)(blk - 192) * 2048; doff = 393216; }
    const size_t idx = so + (size_t)threadIdx.x * 8;
    const float4 f0 = *(const float4*)(src + idx);
    const float4 f1 = *(const float4*)(src + idx + 4);
    uint4 o;
    o.x = pack2(f0.x, f0.y); o.y = pack2(f0.z, f0.w);
    o.z = pack2(f1.x, f1.y); o.w = pack2(f1.z, f1.w);
    *(uint4*)(wb + doff + idx) = o;
}

// ---------------------------------------------------------------------------
// Cast x (16.78M f32) -> bf16. 8192 blocks x 2048 elems.
// ---------------------------------------------------------------------------
__global__ __launch_bounds__(256) void k_castx(
    const float* __restrict__ x, short* __restrict__ xb)
{
    const size_t i = ((size_t)blockIdx.x * 256 + threadIdx.x) * 8;
    const float4 f0 = *(const float4*)(x + i);
    const float4 f1 = *(const float4*)(x + i + 4);
    uint4 o;
    o.x = pack2(f0.x, f0.y); o.y = pack2(f0.z, f0.w);
    o.z = pack2(f1.x, f1.y); o.w = pack2(f1.z, f1.w);
    *(uint4*)(xb + i) = o;
}

// ---------------------------------------------------------------------------
// MFMA GEMM: C[M][ldc] = A[M][256] @ Bw[N][256]^T + bias. A, Bw bf16.
// Tile 128x128, BK=64, 4 K-tiles, double-buffered LDS staged via
// global_load_lds (linear dest, XOR-swizzled SOURCE granule; reads re-apply
// the XOR). 4 waves x 64x64 (acc[4][4]).
// OUTMODE: 0 = f32 linear, 1 = bf16 linear, 2 = kv-split:
//   cols 0..255  -> Cdst[row*256+col] bf16           (K, row-major)
//   cols 256..511-> Vdst[((b*4+h)*64+d)*256+p] bf16  (V transposed per (b,h))
// ---------------------------------------------------------------------------
template<int OUTMODE>
__global__ __launch_bounds__(256, 2) void k_gemm(
    const short* __restrict__ Asrc, const short* __restrict__ Bw,
    const float* __restrict__ bias, void* __restrict__ Cdst,
    short* __restrict__ Vdst, int ldc, int nbn)
{
    __shared__ short As[2][128 * 64];
    __shared__ short Bs[2][128 * 64];

    const int tid = threadIdx.x;
    const int q8 = gridDim.x >> 3;
    const int bid = (blockIdx.x & 7) * q8 + (blockIdx.x >> 3);
    const int bm = bid / nbn, bn = bid % nbn;
    const size_t m0 = (size_t)bm * 128, n0 = (size_t)bn * 128;
    const int wid = tid >> 6, lane = tid & 63;
    const int wr = wid >> 1, wc = wid & 1;
    const int g = lane >> 4, r = lane & 15;
    const int rowc = lane >> 3, gran = lane & 7;   // staging: 8 rows x 8 granules

    f32x4 acc[4][4];
    #pragma unroll
    for (int mi = 0; mi < 4; ++mi)
        #pragma unroll
        for (int nj = 0; nj < 4; ++nj) acc[mi][nj] = (f32x4)0.f;

    // wave 'wid' stages rows [wid*32, wid*32+32) of both A and B tiles.
    auto STAGE = [&](int kt, int bufi) {
        const int k0 = kt * 64;
        #pragma unroll
        for (int i = 0; i < 4; ++i) {
            const int rbase = wid * 32 + i * 8;
            const int row = rbase + rowc;
            const int sg = gran ^ (row & 7);       // pre-swizzled source granule
            GLOAD16(Asrc + (m0 + row) * 256 + k0 + sg * 8, &As[bufi][rbase * 64]);
            GLOAD16(Bw   + (n0 + row) * 256 + k0 + sg * 8, &Bs[bufi][rbase * 64]);
        }
    };

    auto COMPUTE = [&](int bufi) {
        #pragma unroll
        for (int ks = 0; ks < 2; ++ks) {
            const int ke = ks * 32 + g * 8;
            bf16x8 a[4], b[4];
            #pragma unroll
            for (int mi = 0; mi < 4; ++mi) {
                const int row = wr * 64 + mi * 16 + r;
                a[mi] = *(const bf16x8*)&As[bufi][row * 64 + (ke ^ ((row & 7) << 3))];
            }
            #pragma unroll
            for (int nj = 0; nj < 4; ++nj) {
                const int row = wc * 64 + nj * 16 + r;
                b[nj] = *(const bf16x8*)&Bs[bufi][row * 64 + (ke ^ ((row & 7) << 3))];
            }
            #pragma unroll
            for (int mi = 0; mi < 4; ++mi)
                #pragma unroll
                for (int nj = 0; nj < 4; ++nj)
                    acc[mi][nj] = __builtin_amdgcn_mfma_f32_16x16x32_bf16(
                        a[mi], b[nj], acc[mi][nj], 0, 0, 0);
        }
    };

    STAGE(0, 0);
    __syncthreads();
    #pragma unroll
    for (int kt = 0; kt < 4; ++kt) {
        const int cur = kt & 1;
        if (kt < 3) STAGE(kt + 1, cur ^ 1);   // prefetch next tile (in flight)
        COMPUTE(cur);
        __syncthreads();                       // drains vmcnt + lgkmcnt
    }

    #pragma unroll
    for (int nj = 0; nj < 4; ++nj) {
        const size_t col = n0 + wc * 64 + nj * 16 + r;
        const float bv = bias[col];
        #pragma unroll
        for (int mi = 0; mi < 4; ++mi) {
            const size_t row = m0 + wr * 64 + mi * 16 + g * 4;
            #pragma unroll
            for (int e = 0; e < 4; ++e) {
                const float v = acc[mi][nj][e] + bv;
                const size_t rr = row + e;
                if (OUTMODE == 0) ((float*)Cdst)[rr * ldc + col] = v;
                else if (OUTMODE == 1) ((short*)Cdst)[rr * ldc + col] = (short)f2bf(v);
                else {
                    const int colk = (int)col - 256;
                    if (colk < 0) ((short*)Cdst)[rr * 256 + col] = (short)f2bf(v);
                    else {
                        const int hh = colk >> 6, dd = colk & 63;
                        Vdst[((((rr >> 8) * 4 + hh) * 64 + dd) << 8) + (rr & 255)] = (short)f2bf(v);
                    }
                }
            }
        }
    }
}

// ---------------------------------------------------------------------------
// Window attention + residual + LN + pool (unchanged).
// ---------------------------------------------------------------------------
__global__ __launch_bounds__(256) void k_win2(
    const short* __restrict__ qkvb, const float* __restrict__ x,
    const float* __restrict__ gnw, const float* __restrict__ gnb,
    short* __restrict__ lnb, short* __restrict__ pooledb)
{
    __shared__ float qk[16][772];
    __shared__ float sm[4][16][16];

    const int tid = threadIdx.x;
    const int blk = blockIdx.x;
    const int b = blk >> 8, win = blk & 255;
    const int ghi = win >> 4, gwi = win & 15;
    const size_t nb = (size_t)b * 4096;

    {
        const int t = tid >> 4, l16 = tid & 15;
        const int n = (ghi * 4 + (t >> 2)) * 64 + gwi * 4 + (t & 3);
        const short* gp = qkvb + (nb + n) * 768;
        #pragma unroll
        for (int j = 0; j < 6; ++j) {
            const int c16 = l16 + j * 16;
            const uint4 u = *(const uint4*)(gp + c16 * 8);
            float4 a, c;
            a.x = bflo(u.x); a.y = bfhi(u.x); a.z = bflo(u.y); a.w = bfhi(u.y);
            c.x = bflo(u.z); c.y = bfhi(u.z); c.z = bflo(u.w); c.w = bfhi(u.w);
            *(float4*)&qk[t][c16 * 8] = a;
            *(float4*)&qk[t][c16 * 8 + 4] = c;
        }
    }
    __syncthreads();

    {
        const int h = tid >> 6, q = (tid >> 2) & 15, r = tid & 3;
        float4 qv[16];
        const float4* qrow = (const float4*)&qk[q][h * 64];
        #pragma unroll
        for (int i = 0; i < 16; ++i) qv[i] = qrow[i];
        #pragma unroll
        for (int i = 0; i < 4; ++i) {
            const int kt = i * 4 + r;
            const float4* krow = (const float4*)&qk[kt][256 + h * 64];
            float acc = 0.f;
            #pragma unroll
            for (int c4 = 0; c4 < 16; ++c4) {
                const float4 kk = krow[c4];
                acc += qv[c4].x * kk.x + qv[c4].y * kk.y + qv[c4].z * kk.z + qv[c4].w * kk.w;
            }
            sm[h][q][kt] = acc * SCALE;
        }
    }
    __syncthreads();

    if (tid < 64) {
        const int h = tid >> 4, q = tid & 15;
        float4* sp = (float4*)&sm[h][q][0];
        float4 s0 = sp[0], s1 = sp[1], s2 = sp[2], s3 = sp[3];
        float m = fmaxf(fmaxf(fmaxf(fmaxf(s0.x, s0.y), fmaxf(s0.z, s0.w)),
                              fmaxf(fmaxf(s1.x, s1.y), fmaxf(s1.z, s1.w))),
                        fmaxf(fmaxf(fmaxf(s2.x, s2.y), fmaxf(s2.z, s2.w)),
                              fmaxf(fmaxf(s3.x, s3.y), fmaxf(s3.z, s3.w))));
        s0.x = __expf(s0.x - m); s0.y = __expf(s0.y - m); s0.z = __expf(s0.z - m); s0.w = __expf(s0.w - m);
        s1.x = __expf(s1.x - m); s1.y = __expf(s1.y - m); s1.z = __expf(s1.z - m); s1.w = __expf(s1.w - m);
        s2.x = __expf(s2.x - m); s2.y = __expf(s2.y - m); s2.z = __expf(s2.z - m); s2.w = __expf(s2.w - m);
        s3.x = __expf(s3.x - m); s3.y = __expf(s3.y - m); s3.z = __expf(s3.z - m); s3.w = __expf(s3.w - m);
        const float l = s0.x + s0.y + s0.z + s0.w + s1.x + s1.y + s1.z + s1.w
                      + s2.x + s2.y + s2.z + s2.w + s3.x + s3.y + s3.z + s3.w;
        const float inv = 1.f / l;
        s0.x *= inv; s0.y *= inv; s0.z *= inv; s0.w *= inv;
        s1.x *= inv; s1.y *= inv; s1.z *= inv; s1.w *= inv;
        s2.x *= inv; s2.y *= inv; s2.z *= inv; s2.w *= inv;
        s3.x *= inv; s3.y *= inv; s3.z *= inv; s3.w *= inv;
        sp[0] = s0; sp[1] = s1; sp[2] = s2; sp[3] = s3;
    }
    __syncthreads();

    {
        const int h = tid >> 6, d = tid & 63;
        float v[16];
        #pragma unroll
        for (int kt = 0; kt < 16; ++kt) v[kt] = qk[kt][512 + h * 64 + d];
        #pragma unroll
        for (int q = 0; q < 16; ++q) {
            const float4* sp = (const float4*)&sm[h][q][0];
            const float4 a0 = sp[0], a1 = sp[1], a2 = sp[2], a3 = sp[3];
            float o = a0.x * v[0] + a0.y * v[1] + a0.z * v[2] + a0.w * v[3]
                    + a1.x * v[4] + a1.y * v[5] + a1.z * v[6] + a1.w * v[7]
                    + a2.x * v[8] + a2.y * v[9] + a2.z * v[10] + a2.w * v[11]
                    + a3.x * v[12] + a3.y * v[13] + a3.z * v[14] + a3.w * v[15];
            const int n = (ghi * 4 + (q >> 2)) * 64 + gwi * 4 + (q & 3);
            const float xr = x[(nb + n) * 256 + h * 64 + d];
            qk[q][h * 64 + d] = o + xr;
        }
    }
    __syncthreads();

    {
        const int wv = tid >> 6, lane = tid & 63;
        const float4 gw = ((const float4*)gnw)[lane];
        const float4 gb = ((const float4*)gnb)[lane];
        #pragma unroll
        for (int i = 0; i < 4; ++i) {
            const int t = wv * 4 + i;
            const float4 zv = *(const float4*)&qk[t][lane * 4];
            float ssum = zv.x + zv.y + zv.z + zv.w;
            for (int off = 1; off < 64; off <<= 1) ssum += __shfl_xor(ssum, off);
            const float u = ssum * (1.f / 256.f);
            const float dx = zv.x - u, dy = zv.y - u, dz = zv.z - u, dw = zv.w - u;
            float vsum = dx * dx + dy * dy + dz * dz + dw * dw;
            for (int off = 1; off < 64; off <<= 1) vsum += __shfl_xor(vsum, off);
            const float rinv = rsqrtf(vsum * (1.f / 256.f) + LN_EPS);
            float4 y;
            y.x = gw.x * dx * rinv + gb.x;
            y.y = gw.y * dy * rinv + gb.y;
            y.z = gw.z * dz * rinv + gb.z;
            y.w = gw.w * dw * rinv + gb.w;
            *(float4*)&qk[t][lane * 4] = y;
            const int n = (ghi * 4 + (t >> 2)) * 64 + gwi * 4 + (t & 3);
            short4 sv;
            sv.x = (short)f2bf(y.x); sv.y = (short)f2bf(y.y);
            sv.z = (short)f2bf(y.z); sv.w = (short)f2bf(y.w);
            *(short4*)(lnb + (nb + n) * 256 + lane * 4) = sv;
        }
    }
    __syncthreads();

    {
        float ps = 0.f;
        #pragma unroll
        for (int t = 0; t < 16; ++t) ps += qk[t][tid];
        pooledb[((size_t)b * 256 + win) * 256 + tid] = (short)f2bf(ps * (1.f / 16.f));
    }
}

// ---------------------------------------------------------------------------
// Pooled global attention via MFMA. 512 threads / 8 waves, each wave owns 16
// q-rows (block covers 128). LDS 137KB -> 1 block/CU but 2 waves/SIMD.
// ---------------------------------------------------------------------------
#define CP 280
__global__ __launch_bounds__(512, 1) void k_glb(
    const short* __restrict__ qgb, const short* __restrict__ kb,
    const short* __restrict__ vtb, const short* __restrict__ lnb,
    short* __restrict__ gxb)
{
    __shared__ short Ks[256 * 64];
    __shared__ short Vt[64 * 256];
    __shared__ short Pl[8][16 * CP];

    const int tid = threadIdx.x;
    const int bid = (blockIdx.x & 7) * 256 + (blockIdx.x >> 3);
    const int bh = bid >> 5, qt = bid & 31;
    const int b = bh >> 2, h = bh & 3;
    const int q0 = qt * 128;
    const size_t nb = (size_t)b * 4096;

    // stage K [256 keys][64 d], swizzled (2048 granules / 512 threads)
    #pragma unroll
    for (int i = 0; i < 4; ++i) {
        const int c = i * 512 + tid;
        const int p = c >> 3, d8 = (c & 7) * 8;
        const uint4 u = *(const uint4*)(kb + ((size_t)(b * 256 + p)) * 256 + h * 64 + d8);
        *(uint4*)&Ks[p * 64 + (d8 ^ ((p & 7) << 3))] = u;
    }
    // stage V^T [64 d][256 keys], swizzled
    const short* vsrc = vtb + (size_t)bh * 16384;
    #pragma unroll
    for (int i = 0; i < 4; ++i) {
        const int c = i * 512 + tid;
        const int d = c >> 5, k8 = (c & 31) * 8;
        const uint4 u = *(const uint4*)(vsrc + d * 256 + k8);
        *(uint4*)&Vt[d * 256 + (k8 ^ ((d & 7) << 3))] = u;
    }
    __syncthreads();

    const int w = tid >> 6, lane = tid & 63;
    const int g = lane >> 4, l15 = lane & 15;

    // Q A-fragments straight from global: wave w owns q-rows q0+w*16..+15
    bf16x8 aq[2];
    {
        const int n = q0 + w * 16 + l15;
        const short* qp = qgb + (nb + n) * 256 + h * 64 + g * 8;
        aq[0] = *(const bf16x8*)qp;
        aq[1] = *(const bf16x8*)(qp + 32);
    }

    // S = Q K^T : acc[nt] covers q-rows (4g+e), keys nt*16+l15
    f32x4 acc[16];
    #pragma unroll
    for (int nt = 0; nt < 16; ++nt) acc[nt] = (f32x4)0.f;

    #pragma unroll
    for (int nt = 0; nt < 16; ++nt) {
        const int key = nt * 16 + l15;
        const int sw = (key & 7) << 3;
        const bf16x8 bk0 = *(const bf16x8*)&Ks[key * 64 + ((g * 8) ^ sw)];
        const bf16x8 bk1 = *(const bf16x8*)&Ks[key * 64 + ((g * 8 + 32) ^ sw)];
        acc[nt] = __builtin_amdgcn_mfma_f32_16x16x32_bf16(aq[0], bk0, acc[nt], 0, 0, 0);
        acc[nt] = __builtin_amdgcn_mfma_f32_16x16x32_bf16(aq[1], bk1, acc[nt], 0, 0, 0);
    }

    // exp (no max-sub; scores small), row-sum partials, unnormalized P -> LDS
    float rs[4];
    short* Pw = &Pl[w][0];
    #pragma unroll
    for (int e = 0; e < 4; ++e) {
        const int prow = (g * 4 + e) * CP;
        float rsum = 0.f;
        #pragma unroll
        for (int nt = 0; nt < 16; ++nt) {
            const float p = __expf(acc[nt][e] * SCALE);
            rsum += p;
            Pw[prow + nt * 16 + l15] = (short)f2bf(p);
        }
        rs[e] = rsum;
    }
    #pragma unroll
    for (int e = 0; e < 4; ++e) {
        float v = rs[e];
        v += __shfl_xor(v, 1); v += __shfl_xor(v, 2);
        v += __shfl_xor(v, 4); v += __shfl_xor(v, 8);
        rs[e] = v;
    }

    // O = P V (unnormalized), keys as K-dim in 8 steps of 32
    f32x4 oc[4];
    #pragma unroll
    for (int nt = 0; nt < 4; ++nt) oc[nt] = (f32x4)0.f;

    #pragma unroll
    for (int ks = 0; ks < 8; ++ks) {
        const int kc = ks * 32 + g * 8;
        const bf16x8 a0 = *(const bf16x8*)&Pw[l15 * CP + kc];
        #pragma unroll
        for (int nt = 0; nt < 4; ++nt) {
            const int d = nt * 16 + l15;
            const bf16x8 bv = *(const bf16x8*)&Vt[d * 256 + (kc ^ ((d & 7) << 3))];
            oc[nt] = __builtin_amdgcn_mfma_f32_16x16x32_bf16(a0, bv, oc[nt], 0, 0, 0);
        }
    }

    // epilogue: normalize, residual, bf16 store
    #pragma unroll
    for (int e = 0; e < 4; ++e) {
        const float inv = 1.f / rs[e];
        const int n = q0 + w * 16 + g * 4 + e;
        const size_t base = (nb + n) * 256 + h * 64;
        #pragma unroll
        for (int nt = 0; nt < 4; ++nt) {
            const int d = nt * 16 + l15;
            gxb[base + d] = (short)f2bf(oc[nt][e] * inv + bf2f(lnb[base + d]));
        }
    }
}

// ---------------------------------------------------------------------------
extern "C" void kernel_launch(void* const* d_in, const int* in_sizes, int n_in,
                              void* d_out, int out_size, void* d_ws, size_t ws_size,
                              hipStream_t stream)
{
    (void)in_sizes; (void)n_in; (void)out_size; (void)ws_size;
    const float* x     = (const float*)d_in[0];
    const float* wqkv  = (const float*)d_in[1];
    const float* bqkv  = (const float*)d_in[2];
    const float* wq    = (const float*)d_in[3];
    const float* bq    = (const float*)d_in[4];
    const float* wkv   = (const float*)d_in[5];
    const float* bkv   = (const float*)d_in[6];
    const float* wproj = (const float*)d_in[7];
    const float* bproj = (const float*)d_in[8];
    const float* gnw   = (const float*)d_in[9];
    const float* gnb   = (const float*)d_in[10];
    float* out = (float*)d_out;

    char* wsb = (char*)d_ws;
    short* wb      = (short*)(wsb + 0);            // cast weights (bf16)
    short* qkvb    = (short*)(wsb + 1048576);      // 65536 x 768
    short* lnb     = (short*)(wsb + 101711872);    // 65536 x 256
    short* qgb     = (short*)(wsb + 135266304);    // 65536 x 256
    short* kb      = (short*)(wsb + 168820736);    // 4096 x 256 (K)
    short* vtb     = (short*)(wsb + 170917888);    // 64bh x 64d x 256p (V^T)
    short* pooledb = (short*)(wsb + 173015040);    // 4096 x 256
    short* gxb     = (short*)(wsb + 175112192);    // 65536 x 256 bf16
    short* xb      = (short*)(wsb + 208666624);    // 65536 x 256 bf16 (x cast)

    k_castw<<<dim3(224),  dim3(256), 0, stream>>>(wqkv, wq, wkv, wproj, wb);
    k_castx<<<dim3(8192), dim3(256), 0, stream>>>(x, xb);
    // qkv = x @ Wqkv^T + b            (65536 x 768, K=256)
    k_gemm<1><<<dim3(3072), dim3(256), 0, stream>>>(xb, wb, bqkv, qkvb, nullptr, 768, 6);
    // window attention + LN + pool
    k_win2<<<dim3(4096), dim3(256), 0, stream>>>(qkvb, x, gnw, gnb, lnb, pooledb);
    // qg = ln @ Wq^T + b              (65536 x 256)
    k_gemm<1><<<dim3(1024), dim3(256), 0, stream>>>(lnb, wb + 196608, bq, qgb, nullptr, 256, 2);
    // kv = pooled @ Wkv^T + b, split K / V^T
    k_gemm<2><<<dim3(128), dim3(256), 0, stream>>>(pooledb, wb + 262144, bkv, kb, vtb, 512, 4);
    // pooled global attention + residual (MFMA)
    k_glb<<<dim3(2048), dim3(512), 0, stream>>>(qgb, kb, vtb, lnb, gxb);
    // out = gx @ Wproj^T + b          (65536 x 256, f32 out)
    k_gemm<0><<<dim3(1024), dim3(256), 0, stream>>>(gxb, wb + 393216, bproj, out, nullptr, 256, 2);
}